// Round 7
// baseline (2212.351 us; speedup 1.0000x reference)
//
#include <hip/hip_runtime.h>
#include <cstdio>

#define N_TOK 16384
#define CDIM  512

typedef unsigned short ushort_t;
typedef __attribute__((ext_vector_type(8))) __bf16 bf16x8;
typedef __attribute__((ext_vector_type(4))) float f32x4;

// ---------------------------------------------------------------- helpers
__device__ __forceinline__ ushort_t f2bf(float f) {
  union { float f; unsigned u; } v; v.f = f;
  unsigned r = v.u + 0x7FFFu + ((v.u >> 16) & 1u);   // RN-even
  return (ushort_t)(r >> 16);
}
__device__ __forceinline__ float bf2f(ushort_t h) {
  union { unsigned u; float f; } v; v.u = ((unsigned)h) << 16;
  return v.f;
}
// x > 0 guaranteed (relu + 1e-6): x^p = 2^(p*log2(x)) on the HW trans pipe.
__device__ __forceinline__ float fast_pow(float x, float p) {
  return __builtin_amdgcn_exp2f(p * __builtin_amdgcn_logf(x));
}
__device__ __forceinline__ void gl_lds16(const ushort_t* g, ushort_t* l) {
  __builtin_amdgcn_global_load_lds((const __attribute__((address_space(1))) void*)g,
                                   (__attribute__((address_space(3))) void*)l, 16, 0, 0);
}

// ---------------------------------------------------------------- zero
__global__ void zero_kernel(float* __restrict__ p, int n) {
  int i = blockIdx.x * blockDim.x + threadIdx.x;
  if (i < n) p[i] = 0.f;
}

// ---------------------------------------------------------------- 1/softplus(scale), 512 values
__global__ void sp_kernel(const float* __restrict__ scale, float* __restrict__ inv_s) {
  int i = blockIdx.x * blockDim.x + threadIdx.x;
  if (i < 512) {
    float sc = scale[i];
    float s = (sc > 20.f) ? sc : log1pf(expf(sc));
    inv_s[i] = 1.0f / s;
  }
}

// ---------------------------------------------------------------- fp32 -> bf16 hi/lo planes, chunk-permuted
// Plane layout (K=512): elem (r,k) stored at r*512 + (k>>5)*32 + ((c ^ ((r>>1)&3))*8) + (k&7),
// c = (k>>3)&3. The permute makes LDS fragment reads (row-major, 64B rows) ~conflict-free
// when read back with the matching XOR. global_load_lds copies rows verbatim.
__global__ __launch_bounds__(256) void wsplit_kernel(const float* __restrict__ in,
                                                     ushort_t* __restrict__ hi,
                                                     ushort_t* __restrict__ lo, int n4) {
  int i = blockIdx.x * blockDim.x + threadIdx.x;
  const int stride = gridDim.x * blockDim.x;
  for (; i < n4; i += stride) {
    float4 v = ((const float4*)in)[i];
    const int r = i >> 7;            // row (K=512 -> 128 float4/row)
    const int f = i & 127;
    const int kg = f >> 3;           // 32-elem K-group
    const int c = (f >> 1) & 3;      // 8-elem chunk within group
    const int e = (f & 1) * 4;       // half-chunk
    const int dst = r * 512 + kg * 32 + ((c ^ ((r >> 1) & 3)) * 8) + e;
    ushort4 h, l;
    h.x = f2bf(v.x); l.x = f2bf(v.x - bf2f(h.x));
    h.y = f2bf(v.y); l.y = f2bf(v.y - bf2f(h.y));
    h.z = f2bf(v.z); l.z = f2bf(v.z - bf2f(h.z));
    h.w = f2bf(v.w); l.w = f2bf(v.w - bf2f(h.w));
    *(ushort4*)&hi[dst] = h;
    *(ushort4*)&lo[dst] = l;
  }
}

// ---------------------------------------------------------------- split-bf16 MFMA GEMM
// C[M x Nout] = A[M x K] * B[Nout x K]^T + bias. A fp32 (on-the-fly hi/lo split,
// chunk-permuted ds_write); B pre-split permuted planes via global_load_lds.
// Single-buffer 32KB LDS, launch_bounds(256,4) -> 4-5 blocks/CU.
// Output routing: global col < ncol1 -> C1/b1/ldc1, else C2/b2/ldc2 (col-ncol1).
// 1-D grid = Mtiles*nY, XCD-aware: xcd=id&7, y innermost within xloc.
__global__ __launch_bounds__(256, 4) void gemm_s3w(const float* __restrict__ A,
                                                   const ushort_t* __restrict__ Bh,
                                                   const ushort_t* __restrict__ Bl,
                                                   const float* __restrict__ b1,
                                                   const float* __restrict__ b2,
                                                   float* __restrict__ C1,
                                                   float* __restrict__ C2,
                                                   const int K, const int nY,
                                                   const int ncol1,
                                                   const int ldc1, const int ldc2) {
  __shared__ __align__(16) ushort_t Ash[128 * 32];
  __shared__ __align__(16) ushort_t Asl[128 * 32];
  __shared__ __align__(16) ushort_t Bsh[128 * 32];
  __shared__ __align__(16) ushort_t Bsl[128 * 32];
  const int t = threadIdx.x;
  const int lane = t & 63;
  const int w = t >> 6;
  const int wr = w >> 1, wc = w & 1;

  const int id = blockIdx.x;
  const int xcd = id & 7;
  const int j = id >> 3;
  const int xpc = (int)(gridDim.x) / (nY * 8);   // Mtiles per XCD
  const int xloc = j / nY;
  const int y = j - xloc * nY;
  const size_t bm = (size_t)(xcd * xpc + xloc) * 128;
  const int bn = y * 128;

  const int lr = lane & 15;
  const int ksl = lane >> 4;         // k-slot 0..3 (8 bf16 each)

  f32x4 acc[4][4] = {};
  float4 fa[4];

  auto load_A = [&](int k0) {
#pragma unroll
    for (int i = 0; i < 4; ++i) {
      const int idx = i * 256 + t;
      const int row = idx >> 3, c4 = idx & 7;
      fa[i] = *(const float4*)(A + (bm + row) * (size_t)K + k0 + c4 * 4);
    }
  };
  auto store_A = [&]() {
#pragma unroll
    for (int i = 0; i < 4; ++i) {
      const int idx = i * 256 + t;
      const int row = idx >> 3, c4 = idx & 7;
      const int c = c4 >> 1, half = (c4 & 1) * 4;
      const int off = row * 32 + ((c ^ ((row >> 1) & 3)) * 8) + half;
      ushort4 h, l;
      h.x = f2bf(fa[i].x); l.x = f2bf(fa[i].x - bf2f(h.x));
      h.y = f2bf(fa[i].y); l.y = f2bf(fa[i].y - bf2f(h.y));
      h.z = f2bf(fa[i].z); l.z = f2bf(fa[i].z - bf2f(h.z));
      h.w = f2bf(fa[i].w); l.w = f2bf(fa[i].w - bf2f(h.w));
      *(ushort4*)&Ash[off] = h;
      *(ushort4*)&Asl[off] = l;
    }
  };
  // wave w stages B-plane rows [w*32, w*32+32): stored (permuted) order verbatim
  auto stage_B = [&](int k0) {
    const size_t g = (size_t)(bn + w * 32 + (lane >> 2)) * K + k0 + (lane & 3) * 8;
    gl_lds16(Bh + g,                  &Bsh[(w * 32) * 32]);
    gl_lds16(Bh + g + 16 * (size_t)K, &Bsh[(w * 32 + 16) * 32]);
    gl_lds16(Bl + g,                  &Bsl[(w * 32) * 32]);
    gl_lds16(Bl + g + 16 * (size_t)K, &Bsl[(w * 32 + 16) * 32]);
  };

  const int nsteps = K >> 5;
  load_A(0);
  for (int s = 0; s < nsteps; ++s) {
    __syncthreads();                 // prev step's LDS readers done
    store_A();
    stage_B(s << 5);
    __syncthreads();                 // vmcnt+lgkm drain: LDS ready
    bf16x8 ah[4], al[4], bh[4], bl[4];
#pragma unroll
    for (int i = 0; i < 4; ++i) {
      const int rA = wr * 64 + i * 16 + lr;
      const int oA = rA * 32 + ((ksl ^ ((rA >> 1) & 3)) * 8);
      ah[i] = *(const bf16x8*)&Ash[oA];
      al[i] = *(const bf16x8*)&Asl[oA];
      const int rB = wc * 64 + i * 16 + lr;
      const int oB = rB * 32 + ((ksl ^ ((rB >> 1) & 3)) * 8);
      bh[i] = *(const bf16x8*)&Bsh[oB];
      bl[i] = *(const bf16x8*)&Bsl[oB];
    }
    if (s + 1 < nsteps) load_A((s + 1) << 5);   // prefetch under MFMA
#pragma unroll
    for (int mi = 0; mi < 4; ++mi)
#pragma unroll
      for (int ni = 0; ni < 4; ++ni) {
        acc[mi][ni] = __builtin_amdgcn_mfma_f32_16x16x32_bf16(ah[mi], bh[ni], acc[mi][ni], 0, 0, 0);
        acc[mi][ni] = __builtin_amdgcn_mfma_f32_16x16x32_bf16(ah[mi], bl[ni], acc[mi][ni], 0, 0, 0);
        acc[mi][ni] = __builtin_amdgcn_mfma_f32_16x16x32_bf16(al[mi], bh[ni], acc[mi][ni], 0, 0, 0);
      }
  }

  // epilogue: C/D layout col=lane&15, row=(lane>>4)*4+reg (m89-verified)
  float* Cb; const float* bb_; int ldc, colbase;
  if (bn < ncol1) { Cb = C1; bb_ = b1; ldc = ldc1; colbase = bn; }
  else            { Cb = C2; bb_ = b2; ldc = ldc2; colbase = bn - ncol1; }
  const int rg = (lane >> 4) << 2;
#pragma unroll
  for (int ni = 0; ni < 4; ++ni) {
    const int col = colbase + wc * 64 + ni * 16 + lr;
    const float bs = bb_[col];
#pragma unroll
    for (int mi = 0; mi < 4; ++mi) {
      float* Cp = Cb + (bm + wr * 64 + mi * 16 + rg) * (size_t)ldc + col;
#pragma unroll
      for (int j2 = 0; j2 < 4; ++j2)
        Cp[(size_t)j2 * ldc] = acc[mi][ni][j2] + bs;
    }
  }
}

// ---------------------------------------------------------------- nonlinearity, wave-per-row (shfl-only)
__global__ __launch_bounds__(256) void nonlin2_kernel(float* __restrict__ q,
                                                      float* __restrict__ kv,
                                                      const float* __restrict__ inv_s,
                                                      const float* __restrict__ ff) {
  const int t = threadIdx.x, lane = t & 63, w = t >> 6;
  const int row = blockIdx.x * 4 + w;
  float* qr = q + (size_t)row * 512 + lane * 8;
  float* kr = kv + (size_t)row * 1024 + lane * 8;

  float qv[8], kval[8], is[8], fv[8];
  *(float4*)&qv[0] = *(const float4*)qr;       *(float4*)&qv[4] = *(const float4*)(qr + 4);
  *(float4*)&kval[0] = *(const float4*)kr;     *(float4*)&kval[4] = *(const float4*)(kr + 4);
  *(float4*)&is[0] = *(const float4*)(inv_s + lane * 8);
  *(float4*)&is[4] = *(const float4*)(inv_s + lane * 8 + 4);
  *(float4*)&fv[0] = *(const float4*)(ff + lane * 8);
  *(float4*)&fv[4] = *(const float4*)(ff + lane * 8 + 4);

  float sq = 0.f, sk = 0.f;
#pragma unroll
  for (int i = 0; i < 8; ++i) {
    qv[i] = (fmaxf(qv[i], 0.f) + 1e-6f) * is[i];
    kval[i] = (fmaxf(kval[i], 0.f) + 1e-6f) * is[i];
    sq += qv[i] * qv[i];
    sk += kval[i] * kval[i];
  }
#pragma unroll
  for (int off = 1; off < 64; off <<= 1) {
    sq += __shfl_xor(sq, off);
    sk += __shfl_xor(sk, off);
  }
  const float qn = sqrtf(sq), kn = sqrtf(sk);

  float pq[8], pk[8], sq2 = 0.f, sk2 = 0.f;
#pragma unroll
  for (int i = 0; i < 8; ++i) {
    pq[i] = fast_pow(qv[i], fv[i]);
    pk[i] = fast_pow(kval[i], fv[i]);
    sq2 += pq[i] * pq[i];
    sk2 += pk[i] * pk[i];
  }
#pragma unroll
  for (int off = 1; off < 64; off <<= 1) {
    sq2 += __shfl_xor(sq2, off);
    sk2 += __shfl_xor(sk2, off);
  }
  const float qs = qn / sqrtf(sq2), ks = kn / sqrtf(sk2);
#pragma unroll
  for (int i = 0; i < 8; ++i) { qv[i] = pq[i] * qs; kval[i] = pk[i] * ks; }
  *(float4*)qr = *(float4*)&qv[0];       *(float4*)(qr + 4) = *(float4*)&qv[4];
  *(float4*)kr = *(float4*)&kval[0];     *(float4*)(kr + 4) = *(float4*)&kval[4];
}

// ---------------------------------------------------------------- kv_mat[bh] = k^T v / N  (+ fused ksum)
__global__ __launch_bounds__(256) void kvmat_kernel(const float* __restrict__ kv,
                                                    float* __restrict__ kvm,
                                                    float* __restrict__ ksum) {
  __shared__ float ks[8][64];
  __shared__ float vs[8][64];
  const int bh = blockIdx.y;
  const int b = bh >> 3, h = bh & 7;
  const int chunk = blockIdx.x;
  const int t = threadIdx.x;
  const int tr = (t >> 4) * 4, tc = (t & 15) * 4;
  float acc[4][4] = {};
  float kacc = 0.f;
  size_t rowbase = (size_t)b * N_TOK + (size_t)chunk * 512;
  for (int it = 0; it < 64; ++it) {
    __syncthreads();
#pragma unroll
    for (int l = 0; l < 4; ++l) {
      int idx = l * 256 + t;
      int ri = idx >> 7, ci = idx & 127;
      size_t g = (rowbase + it * 8 + ri) * 1024 + h * 64;
      if (ci < 64) ks[ri][ci] = kv[g + ci];
      else         vs[ri][ci - 64] = kv[g + 512 + (ci - 64)];
    }
    __syncthreads();
    if (t < 64) {     // fused k column-sum (wave 0 only, conflict-free reads)
      float ka = 0.f;
#pragma unroll
      for (int ri = 0; ri < 8; ++ri) ka += ks[ri][t];
      kacc += ka;
    }
#pragma unroll
    for (int ri = 0; ri < 8; ++ri) {
      float a[4], v4[4];
#pragma unroll
      for (int i = 0; i < 4; ++i) a[i] = ks[ri][tr + i];
#pragma unroll
      for (int j = 0; j < 4; ++j) v4[j] = vs[ri][tc + j];
#pragma unroll
      for (int i = 0; i < 4; ++i)
#pragma unroll
        for (int j = 0; j < 4; ++j)
          acc[i][j] = fmaf(a[i], v4[j], acc[i][j]);
    }
  }
  const float scl = 1.0f / (float)N_TOK;
#pragma unroll
  for (int i = 0; i < 4; ++i)
#pragma unroll
    for (int j = 0; j < 4; ++j)
      atomicAdd(&kvm[(size_t)bh * 4096 + (tr + i) * 64 + (tc + j)], acc[i][j] * scl);
  if (t < 64) atomicAdd(&ksum[b * 512 + h * 64 + t], kacc);
}

// ---------------------------------------------------------------- attn with fused z: q <- (q @ kvm) * z
__global__ __launch_bounds__(256) void attn_fz_kernel(float* __restrict__ q,
                                                      const float* __restrict__ kvm,
                                                      const float* __restrict__ ksum) {
  __shared__ float km[64][64];
  __shared__ float qs[64][64];
  __shared__ float kms[64];
  __shared__ float zl[64];
  const int bh = blockIdx.y;
  const int b = bh >> 3, h = bh & 7;
  const int tok0 = blockIdx.x * 64;
  const int t = threadIdx.x;
  const size_t kvm_base = (size_t)bh * 4096;
  const size_t qbase = ((size_t)b * N_TOK + tok0) * 512 + h * 64;
#pragma unroll
  for (int i = 0; i < 16; ++i) {
    int idx = i * 256 + t;
    km[idx >> 6][idx & 63] = kvm[kvm_base + idx];
    qs[idx >> 6][idx & 63] = q[qbase + (size_t)(idx >> 6) * 512 + (idx & 63)];
  }
  if (t < 64) kms[t] = ksum[b * 512 + h * 64 + t];
  __syncthreads();

  {
    const int tok = t >> 2, dq = (t & 3) * 16;
    float p = 0.f;
#pragma unroll
    for (int i = 0; i < 16; ++i) p += qs[tok][dq + i] * kms[dq + i];
    p += __shfl_xor(p, 1);
    p += __shfl_xor(p, 2);
    if ((t & 3) == 0) zl[tok] = 1.0f / (p * (1.0f / (float)N_TOK) + 1e-6f);
  }
  __syncthreads();

  const int d = t & 63, slot = t >> 6;
  for (int i = 0; i < 16; ++i) {
    const int tok = i * 4 + slot;
    float a0 = 0.f, a1 = 0.f, a2 = 0.f, a3 = 0.f;
#pragma unroll
    for (int din = 0; din < 64; din += 4) {
      a0 = fmaf(qs[tok][din + 0], km[din + 0][d], a0);
      a1 = fmaf(qs[tok][din + 1], km[din + 1][d], a1);
      a2 = fmaf(qs[tok][din + 2], km[din + 2][d], a2);
      a3 = fmaf(qs[tok][din + 3], km[din + 3][d], a3);
    }
    q[qbase + (size_t)tok * 512 + d] = ((a0 + a1) + (a2 + a3)) * zl[tok];
  }
}

// ---------------------------------------------------------------- depthwise 5x5 conv on v, += into y
__global__ __launch_bounds__(256) void conv_kernel(const float* __restrict__ kv,
                                                   float* __restrict__ y,
                                                   const float* __restrict__ wconv,
                                                   const float* __restrict__ bconv) {
  __shared__ float vt[20 * 20 * 32];
  const int zidx = blockIdx.z;
  const int bh = zidx >> 1, chalf = zidx & 1;
  const int b = bh >> 3, h = bh & 7;
  const int c0 = chalf * 32;
  const int tx0 = blockIdx.x * 16, ty0 = blockIdx.y * 16;
  const int t = threadIdx.x;
  const int c = t & 31;
  const size_t vbase = (size_t)b * N_TOK * 1024 + 512 + h * 64 + c0 + c;
  for (int i = 0; i < 50; ++i) {
    int idx = i * 256 + t;
    int pix = idx >> 5;
    int lx = pix % 20, ly = pix / 20;
    int gx = tx0 + lx - 2, gy = ty0 + ly - 2;
    float val = 0.f;
    if ((unsigned)gx < 128u && (unsigned)gy < 128u)
      val = kv[vbase + ((size_t)(gy * 128 + gx)) * 1024 - (size_t)c + (size_t)(idx & 31)];
    vt[pix * 32 + (idx & 31)] = val;
  }
  const int dd = c0 + c;
  float w[25];
#pragma unroll
  for (int k = 0; k < 25; ++k) w[k] = wconv[dd * 25 + k];
  const float bb = bconv[dd];
  __syncthreads();
  const int slot = t >> 5;
  for (int i = 0; i < 32; ++i) {
    const int pix = i * 8 + slot;
    const int px = pix & 15, py = pix >> 4;
    float acc = bb;
#pragma unroll
    for (int ky = 0; ky < 5; ++ky)
#pragma unroll
      for (int kx = 0; kx < 5; ++kx)
        acc = fmaf(w[ky * 5 + kx], vt[((py + ky) * 20 + (px + kx)) * 32 + c], acc);
    size_t o = ((size_t)b * N_TOK + (size_t)(ty0 + py) * 128 + (tx0 + px)) * 512 + h * 64 + dd;
    y[o] += acc;
  }
}

// ---------------------------------------------------------------- launch
extern "C" void kernel_launch(void* const* d_in, const int* in_sizes, int n_in,
                              void* d_out, int out_size, void* d_ws, size_t ws_size,
                              hipStream_t stream) {
  (void)n_in; (void)out_size;
  const float* x     = (const float*)d_in[0];
  const float* Wq    = (const float*)d_in[1];
  const float* bq    = (const float*)d_in[2];
  const float* Wkv   = (const float*)d_in[3];
  const float* bkv   = (const float*)d_in[4];
  const float* Wp    = (const float*)d_in[5];
  const float* bp    = (const float*)d_in[6];
  const float* ff    = (const float*)d_in[7];
  const float* scale = (const float*)d_in[8];
  const float* dwc_w = (const float*)d_in[9];
  const float* dwc_b = (const float*)d_in[10];

  const int B = in_sizes[0] / (N_TOK * CDIM);   // 4
  const int M = B * N_TOK;                      // 65536

  // workspace layout: identical to the round-1 known-good 405.3 MB footprint
  float* q    = (float*)d_ws;                          // M x 512
  float* kv   = q + (size_t)M * 512;                   // M x 1024 (k | v)
  float* ksum = kv + (size_t)M * 1024;                 // B x 512
  float* kvm  = ksum + (size_t)B * 512;                // 32 x 64 x 64
  float* z    = kvm + (size_t)B * 8 * 4096;            // 2 MB scratch

  size_t need = ((size_t)M * 1536 + (size_t)B * 512 + (size_t)B * 8 * 4096 +
                 (size_t)B * 8 * N_TOK) * sizeof(float);
  if (ws_size < need) {
    fprintf(stderr, "kernel_launch: ws too small (%zu < %zu)\n", ws_size, need);
    return;
  }

  // scratch carve-outs (no new ws):
  //  - z region (2 MB): wp planes (1 MB) + inv_s (2 KB)
  //  - d_out head (free until final GEMM): combined wq|wkv planes (3 MB)
  ushort_t* wph    = (ushort_t*)z;               // 512x512 permuted planes
  ushort_t* wpl    = wph + 262144;
  float*    inv_s  = z + 262144;                 // after 1 MB of ushorts
  ushort_t* wqkvh  = (ushort_t*)d_out;           // 1536x512 combined hi
  ushort_t* wqkvl  = wqkvh + 1536 * 512;         // combined lo

  const int nsmall = B * 512 + B * 8 * 4096;
  zero_kernel<<<(nsmall + 255) / 256, 256, 0, stream>>>(ksum, nsmall);
  sp_kernel<<<2, 256, 0, stream>>>(scale, inv_s);
  wsplit_kernel<<<64, 256, 0, stream>>>(Wq, wqkvh, wqkvl, 512 * 512 / 4);
  wsplit_kernel<<<128, 256, 0, stream>>>(Wkv, wqkvh + 512 * 512, wqkvl + 512 * 512, 1024 * 512 / 4);
  wsplit_kernel<<<64, 256, 0, stream>>>(Wp, wph, wpl, 512 * 512 / 4);

  // fused q+kv projection: Nout = 1536, cols <512 -> q (ldc 512), else kv (ldc 1024)
  gemm_s3w<<<(M / 128) * 12, 256, 0, stream>>>(x, wqkvh, wqkvl, bq, bkv,
                                               q, kv, CDIM, 12, 512, 512, 1024);

  nonlin2_kernel<<<M / 4, 256, 0, stream>>>(q, kv, inv_s, ff);
  kvmat_kernel<<<dim3(32, B * 8), 256, 0, stream>>>(kv, kvm, ksum);
  attn_fz_kernel<<<dim3(N_TOK / 64, B * 8), 256, 0, stream>>>(q, kvm, ksum);
  conv_kernel<<<dim3(8, 8, B * 8 * 2), 256, 0, stream>>>(kv, q, dwc_w, dwc_b);

  gemm_s3w<<<(M / 128) * 4, 256, 0, stream>>>(q, wph, wpl, bp, bp,
                                              (float*)d_out, (float*)d_out, CDIM, 4, 512, 512, 512);
}

// Round 8
// 1006.179 us; speedup vs baseline: 2.1988x; 2.1988x over previous
//
#include <hip/hip_runtime.h>
#include <cstdio>

#define N_TOK 16384
#define CDIM  512

typedef unsigned short ushort_t;
typedef _Float16 f16;
typedef __attribute__((ext_vector_type(8))) _Float16 f16x8;
typedef __attribute__((ext_vector_type(4))) _Float16 f16x4;
typedef __attribute__((ext_vector_type(4))) float f32x4;

// ---------------------------------------------------------------- helpers
// x > 0 guaranteed (relu + 1e-6): x^p = 2^(p*log2(x)) on the HW trans pipe.
__device__ __forceinline__ float fast_pow(float x, float p) {
  return __builtin_amdgcn_exp2f(p * __builtin_amdgcn_logf(x));
}
__device__ __forceinline__ void gl_lds16(const void* g, void* l) {
  __builtin_amdgcn_global_load_lds((const __attribute__((address_space(1))) void*)g,
                                   (__attribute__((address_space(3))) void*)l, 16, 0, 0);
}

// ---------------------------------------------------------------- zero
__global__ void zero_kernel(float* __restrict__ p, int n) {
  int i = blockIdx.x * blockDim.x + threadIdx.x;
  if (i < n) p[i] = 0.f;
}

// ---------------------------------------------------------------- 1/softplus(scale), 512 values
__global__ void sp_kernel(const float* __restrict__ scale, float* __restrict__ inv_s) {
  int i = blockIdx.x * blockDim.x + threadIdx.x;
  if (i < 512) {
    float sc = scale[i];
    float s = (sc > 20.f) ? sc : log1pf(expf(sc));
    inv_s[i] = 1.0f / s;
  }
}

// ---------------------------------------------------------------- fp32 -> fp16, chunk-permuted (K=512 rows)
// elem (r,k) -> r*512 + (k>>5)*32 + ((c ^ ((r>>1)&3))*8) + (k&7), c=(k>>3)&3.
// Makes LDS fragment reads conflict-free after verbatim global_load_lds staging
// (R7-verified: SQ_LDS_BANK_CONFLICT == 0 with this permute pair).
__global__ __launch_bounds__(256) void cvt_perm_kernel(const float* __restrict__ in,
                                                       f16* __restrict__ out, int n4) {
  int i = blockIdx.x * blockDim.x + threadIdx.x;
  const int stride = gridDim.x * blockDim.x;
  for (; i < n4; i += stride) {
    float4 v = ((const float4*)in)[i];
    const int r = i >> 7;            // row (128 float4 per 512-col row)
    const int f = i & 127;
    const int kg = f >> 3;           // 32-elem K-group
    const int c = (f >> 1) & 3;      // 8-elem chunk within group
    const int e = (f & 1) * 4;       // half-chunk
    const int dst = r * 512 + kg * 32 + ((c ^ ((r >> 1) & 3)) * 8) + e;
    f16x4 h;
    h.x = (f16)v.x; h.y = (f16)v.y; h.z = (f16)v.z; h.w = (f16)v.w;
    *(f16x4*)&out[dst] = h;
  }
}

// ---------------------------------------------------------------- fp16 MFMA GEMM, full-DMA
// C[M x Nout] = A[M x K] * B[Nout x K]^T + bias. A,B pre-converted permuted fp16.
// Both staged via global_load_lds, double-buffered, ONE barrier per K-step.
// Output routing: col < ncol1 -> C1/b1/ldc1 else C2/b2/ldc2.
// 1-D grid = Mtiles*nY, XCD remap: xcd=id&7, y innermost.
__global__ __launch_bounds__(256, 4) void gemm_f16(const f16* __restrict__ A,
                                                   const f16* __restrict__ Bw,
                                                   const float* __restrict__ b1,
                                                   const float* __restrict__ b2,
                                                   float* __restrict__ C1,
                                                   float* __restrict__ C2,
                                                   const int K, const int nY,
                                                   const int ncol1,
                                                   const int ldc1, const int ldc2) {
  __shared__ __align__(16) f16 As[2][128 * 32];
  __shared__ __align__(16) f16 Bs[2][128 * 32];
  const int t = threadIdx.x;
  const int lane = t & 63;
  const int w = t >> 6;
  const int wr = w >> 1, wc = w & 1;

  const int id = blockIdx.x;
  const int xcd = id & 7;
  const int j = id >> 3;
  const int xpc = (int)(gridDim.x) / (nY * 8);   // Mtiles per XCD
  const int xloc = j / nY;
  const int y = j - xloc * nY;
  const size_t bm = (size_t)(xcd * xpc + xloc) * 128;
  const int bn = y * 128;

  const int lr = lane & 15;
  const int ksl = lane >> 4;         // k-slot 0..3

  f32x4 acc[4][4] = {};

  // wave w stages rows [w*32, w*32+32) of A and B tiles (verbatim permuted order)
  auto stage = [&](int k0, int buf) {
    const int rsub = lane >> 2;                  // 0..15
    const int csub = (lane & 3) * 8;
    const size_t ga = (bm + w * 32 + rsub) * (size_t)K + k0 + csub;
    const size_t gb = ((size_t)(bn + w * 32 + rsub)) * K + k0 + csub;
    gl_lds16(A + ga,                  &As[buf][(w * 32) * 32]);
    gl_lds16(A + ga + 16 * (size_t)K, &As[buf][(w * 32 + 16) * 32]);
    gl_lds16(Bw + gb,                  &Bs[buf][(w * 32) * 32]);
    gl_lds16(Bw + gb + 16 * (size_t)K, &Bs[buf][(w * 32 + 16) * 32]);
  };

  const int nsteps = K >> 5;
  stage(0, 0);
  for (int s = 0; s < nsteps; ++s) {
    const int buf = s & 1;
    __syncthreads();                 // drains stage(s,buf); prev readers of buf^1 done
    f16x8 a[4], b[4];
#pragma unroll
    for (int i = 0; i < 4; ++i) {
      const int rA = wr * 64 + i * 16 + lr;
      a[i] = *(const f16x8*)&As[buf][rA * 32 + ((ksl ^ ((rA >> 1) & 3)) * 8)];
      const int rB = wc * 64 + i * 16 + lr;
      b[i] = *(const f16x8*)&Bs[buf][rB * 32 + ((ksl ^ ((rB >> 1) & 3)) * 8)];
    }
    if (s + 1 < nsteps) stage((s + 1) << 5, buf ^ 1);   // DMA under MFMA
#pragma unroll
    for (int mi = 0; mi < 4; ++mi)
#pragma unroll
      for (int ni = 0; ni < 4; ++ni)
        acc[mi][ni] = __builtin_amdgcn_mfma_f32_16x16x32_f16(a[mi], b[ni], acc[mi][ni], 0, 0, 0);
  }

  // epilogue: C/D layout col=lane&15, row=(lane>>4)*4+reg (m89-verified)
  float* Cb; const float* bb_; int ldc, colbase;
  if (bn < ncol1) { Cb = C1; bb_ = b1; ldc = ldc1; colbase = bn; }
  else            { Cb = C2; bb_ = b2; ldc = ldc2; colbase = bn - ncol1; }
  const int rg = (lane >> 4) << 2;
#pragma unroll
  for (int ni = 0; ni < 4; ++ni) {
    const int col = colbase + wc * 64 + ni * 16 + lr;
    const float bs = bb_[col];
#pragma unroll
    for (int mi = 0; mi < 4; ++mi) {
      float* Cp = Cb + (bm + wr * 64 + mi * 16 + rg) * (size_t)ldc + col;
#pragma unroll
      for (int j2 = 0; j2 < 4; ++j2)
        Cp[(size_t)j2 * ldc] = acc[mi][ni][j2] + bs;
    }
  }
}

// ---------------------------------------------------------------- nonlinearity, wave-per-row (shfl-only)
__global__ __launch_bounds__(256) void nonlin2_kernel(float* __restrict__ q,
                                                      float* __restrict__ kv,
                                                      const float* __restrict__ inv_s,
                                                      const float* __restrict__ ff) {
  const int t = threadIdx.x, lane = t & 63, w = t >> 6;
  const int row = blockIdx.x * 4 + w;
  float* qr = q + (size_t)row * 512 + lane * 8;
  float* kr = kv + (size_t)row * 1024 + lane * 8;

  float qv[8], kval[8], is[8], fv[8];
  *(float4*)&qv[0] = *(const float4*)qr;       *(float4*)&qv[4] = *(const float4*)(qr + 4);
  *(float4*)&kval[0] = *(const float4*)kr;     *(float4*)&kval[4] = *(const float4*)(kr + 4);
  *(float4*)&is[0] = *(const float4*)(inv_s + lane * 8);
  *(float4*)&is[4] = *(const float4*)(inv_s + lane * 8 + 4);
  *(float4*)&fv[0] = *(const float4*)(ff + lane * 8);
  *(float4*)&fv[4] = *(const float4*)(ff + lane * 8 + 4);

  float sq = 0.f, sk = 0.f;
#pragma unroll
  for (int i = 0; i < 8; ++i) {
    qv[i] = (fmaxf(qv[i], 0.f) + 1e-6f) * is[i];
    kval[i] = (fmaxf(kval[i], 0.f) + 1e-6f) * is[i];
    sq += qv[i] * qv[i];
    sk += kval[i] * kval[i];
  }
#pragma unroll
  for (int off = 1; off < 64; off <<= 1) {
    sq += __shfl_xor(sq, off);
    sk += __shfl_xor(sk, off);
  }
  const float qn = sqrtf(sq), kn = sqrtf(sk);

  float pq[8], pk[8], sq2 = 0.f, sk2 = 0.f;
#pragma unroll
  for (int i = 0; i < 8; ++i) {
    pq[i] = fast_pow(qv[i], fv[i]);
    pk[i] = fast_pow(kval[i], fv[i]);
    sq2 += pq[i] * pq[i];
    sk2 += pk[i] * pk[i];
  }
#pragma unroll
  for (int off = 1; off < 64; off <<= 1) {
    sq2 += __shfl_xor(sq2, off);
    sk2 += __shfl_xor(sk2, off);
  }
  const float qs = qn / sqrtf(sq2), ks = kn / sqrtf(sk2);
#pragma unroll
  for (int i = 0; i < 8; ++i) { qv[i] = pq[i] * qs; kval[i] = pk[i] * ks; }
  *(float4*)qr = *(float4*)&qv[0];       *(float4*)(qr + 4) = *(float4*)&qv[4];
  *(float4*)kr = *(float4*)&kval[0];     *(float4*)(kr + 4) = *(float4*)&kval[4];
}

// ---------------------------------------------------------------- kv_mat[bh] = k^T v / N  (+ fused ksum)
__global__ __launch_bounds__(256) void kvmat_kernel(const float* __restrict__ kv,
                                                    float* __restrict__ kvm,
                                                    float* __restrict__ ksum) {
  __shared__ float ks[8][64];
  __shared__ float vs[8][64];
  const int bh = blockIdx.y;
  const int b = bh >> 3, h = bh & 7;
  const int chunk = blockIdx.x;
  const int t = threadIdx.x;
  const int tr = (t >> 4) * 4, tc = (t & 15) * 4;
  float acc[4][4] = {};
  float kacc = 0.f;
  size_t rowbase = (size_t)b * N_TOK + (size_t)chunk * 512;
  for (int it = 0; it < 64; ++it) {
    __syncthreads();
#pragma unroll
    for (int l = 0; l < 4; ++l) {
      int idx = l * 256 + t;
      int ri = idx >> 7, ci = idx & 127;
      size_t g = (rowbase + it * 8 + ri) * 1024 + h * 64;
      if (ci < 64) ks[ri][ci] = kv[g + ci];
      else         vs[ri][ci - 64] = kv[g + 512 + (ci - 64)];
    }
    __syncthreads();
    if (t < 64) {     // fused k column-sum (wave 0, conflict-free)
      float ka = 0.f;
#pragma unroll
      for (int ri = 0; ri < 8; ++ri) ka += ks[ri][t];
      kacc += ka;
    }
#pragma unroll
    for (int ri = 0; ri < 8; ++ri) {
      float a[4], v4[4];
#pragma unroll
      for (int i = 0; i < 4; ++i) a[i] = ks[ri][tr + i];
#pragma unroll
      for (int j = 0; j < 4; ++j) v4[j] = vs[ri][tc + j];
#pragma unroll
      for (int i = 0; i < 4; ++i)
#pragma unroll
        for (int j = 0; j < 4; ++j)
          acc[i][j] = fmaf(a[i], v4[j], acc[i][j]);
    }
  }
  const float scl = 1.0f / (float)N_TOK;
#pragma unroll
  for (int i = 0; i < 4; ++i)
#pragma unroll
    for (int j = 0; j < 4; ++j)
      atomicAdd(&kvm[(size_t)bh * 4096 + (tr + i) * 64 + (tc + j)], acc[i][j] * scl);
  if (t < 64) atomicAdd(&ksum[b * 512 + h * 64 + t], kacc);
}

// ---------------------------------------------------------------- attn with fused z: q <- (q @ kvm) * z
__global__ __launch_bounds__(256) void attn_fz_kernel(float* __restrict__ q,
                                                      const float* __restrict__ kvm,
                                                      const float* __restrict__ ksum) {
  __shared__ float km[64][64];
  __shared__ float qs[64][64];
  __shared__ float kms[64];
  __shared__ float zl[64];
  const int bh = blockIdx.y;
  const int b = bh >> 3, h = bh & 7;
  const int tok0 = blockIdx.x * 64;
  const int t = threadIdx.x;
  const size_t kvm_base = (size_t)bh * 4096;
  const size_t qbase = ((size_t)b * N_TOK + tok0) * 512 + h * 64;
#pragma unroll
  for (int i = 0; i < 16; ++i) {
    int idx = i * 256 + t;
    km[idx >> 6][idx & 63] = kvm[kvm_base + idx];
    qs[idx >> 6][idx & 63] = q[qbase + (size_t)(idx >> 6) * 512 + (idx & 63)];
  }
  if (t < 64) kms[t] = ksum[b * 512 + h * 64 + t];
  __syncthreads();

  {
    const int tok = t >> 2, dq = (t & 3) * 16;
    float p = 0.f;
#pragma unroll
    for (int i = 0; i < 16; ++i) p += qs[tok][dq + i] * kms[dq + i];
    p += __shfl_xor(p, 1);
    p += __shfl_xor(p, 2);
    if ((t & 3) == 0) zl[tok] = 1.0f / (p * (1.0f / (float)N_TOK) + 1e-6f);
  }
  __syncthreads();

  const int d = t & 63, slot = t >> 6;
  for (int i = 0; i < 16; ++i) {
    const int tok = i * 4 + slot;
    float a0 = 0.f, a1 = 0.f, a2 = 0.f, a3 = 0.f;
#pragma unroll
    for (int din = 0; din < 64; din += 4) {
      a0 = fmaf(qs[tok][din + 0], km[din + 0][d], a0);
      a1 = fmaf(qs[tok][din + 1], km[din + 1][d], a1);
      a2 = fmaf(qs[tok][din + 2], km[din + 2][d], a2);
      a3 = fmaf(qs[tok][din + 3], km[din + 3][d], a3);
    }
    q[qbase + (size_t)tok * 512 + d] = ((a0 + a1) + (a2 + a3)) * zl[tok];
  }
}

// ---------------------------------------------------------------- depthwise 5x5 conv on v, += into y
__global__ __launch_bounds__(256) void conv_kernel(const float* __restrict__ kv,
                                                   float* __restrict__ y,
                                                   const float* __restrict__ wconv,
                                                   const float* __restrict__ bconv) {
  __shared__ float vt[20 * 20 * 32];
  const int zidx = blockIdx.z;
  const int bh = zidx >> 1, chalf = zidx & 1;
  const int b = bh >> 3, h = bh & 7;
  const int c0 = chalf * 32;
  const int tx0 = blockIdx.x * 16, ty0 = blockIdx.y * 16;
  const int t = threadIdx.x;
  const int c = t & 31;
  const size_t vbase = (size_t)b * N_TOK * 1024 + 512 + h * 64 + c0 + c;
  for (int i = 0; i < 50; ++i) {
    int idx = i * 256 + t;
    int pix = idx >> 5;
    int lx = pix % 20, ly = pix / 20;
    int gx = tx0 + lx - 2, gy = ty0 + ly - 2;
    float val = 0.f;
    if ((unsigned)gx < 128u && (unsigned)gy < 128u)
      val = kv[vbase + ((size_t)(gy * 128 + gx)) * 1024 - (size_t)c + (size_t)(idx & 31)];
    vt[pix * 32 + (idx & 31)] = val;
  }
  const int dd = c0 + c;
  float w[25];
#pragma unroll
  for (int k = 0; k < 25; ++k) w[k] = wconv[dd * 25 + k];
  const float bb = bconv[dd];
  __syncthreads();
  const int slot = t >> 5;
  for (int i = 0; i < 32; ++i) {
    const int pix = i * 8 + slot;
    const int px = pix & 15, py = pix >> 4;
    float acc = bb;
#pragma unroll
    for (int ky = 0; ky < 5; ++ky)
#pragma unroll
      for (int kx = 0; kx < 5; ++kx)
        acc = fmaf(w[ky * 5 + kx], vt[((py + ky) * 20 + (px + kx)) * 32 + c], acc);
    size_t o = ((size_t)b * N_TOK + (size_t)(ty0 + py) * 128 + (tx0 + px)) * 512 + h * 64 + dd;
    y[o] += acc;
  }
}

// ---------------------------------------------------------------- launch
extern "C" void kernel_launch(void* const* d_in, const int* in_sizes, int n_in,
                              void* d_out, int out_size, void* d_ws, size_t ws_size,
                              hipStream_t stream) {
  (void)n_in; (void)out_size;
  const float* x     = (const float*)d_in[0];
  const float* Wq    = (const float*)d_in[1];
  const float* bq    = (const float*)d_in[2];
  const float* Wkv   = (const float*)d_in[3];
  const float* bkv   = (const float*)d_in[4];
  const float* Wp    = (const float*)d_in[5];
  const float* bp    = (const float*)d_in[6];
  const float* ff    = (const float*)d_in[7];
  const float* scale = (const float*)d_in[8];
  const float* dwc_w = (const float*)d_in[9];
  const float* dwc_b = (const float*)d_in[10];

  const int B = in_sizes[0] / (N_TOK * CDIM);   // 4
  const int M = B * N_TOK;                      // 65536

  // workspace layout: round-1 known-good 405.3 MB footprint
  float* q    = (float*)d_ws;                          // M x 512  (becomes y)
  float* kv   = q + (size_t)M * 512;                   // M x 1024 (k | v)
  float* ksum = kv + (size_t)M * 1024;                 // B x 512
  float* kvm  = ksum + (size_t)B * 512;                // 32 x 64 x 64
  float* z    = kvm + (size_t)B * 8 * 4096;            // 2 MB scratch

  size_t need = ((size_t)M * 1536 + (size_t)B * 512 + (size_t)B * 8 * 4096 +
                 (size_t)B * 8 * N_TOK) * sizeof(float);
  if (ws_size < need) {
    fprintf(stderr, "kernel_launch: ws too small (%zu < %zu)\n", ws_size, need);
    return;
  }

  // scratch carve-outs:
  //  - d_out head (free until final GEMM): x16 (64 MB) + wqkv16 (1.5 MB)
  //  - z region: wp16 (0.5 MB) + inv_s (2 KB)
  //  - kv region head (dead after conv): y16 (64 MB)
  f16* x16    = (f16*)d_out;
  f16* wqkv16 = x16 + (size_t)M * 512;
  f16* wp16   = (f16*)z;
  float* inv_s = z + 131072;                     // after 512 KB of f16
  f16* y16    = (f16*)kv;

  const int nsmall = B * 512 + B * 8 * 4096;
  zero_kernel<<<(nsmall + 255) / 256, 256, 0, stream>>>(ksum, nsmall);
  sp_kernel<<<2, 256, 0, stream>>>(scale, inv_s);
  cvt_perm_kernel<<<4096, 256, 0, stream>>>(x, x16, M * 512 / 4);
  cvt_perm_kernel<<<256, 256, 0, stream>>>(Wq, wqkv16, 512 * 512 / 4);
  cvt_perm_kernel<<<512, 256, 0, stream>>>(Wkv, wqkv16 + 512 * 512, 1024 * 512 / 4);
  cvt_perm_kernel<<<256, 256, 0, stream>>>(Wp, wp16, 512 * 512 / 4);

  // fused q+kv projection: Nout = 1536; cols <512 -> q (ldc 512), else kv (ldc 1024)
  gemm_f16<<<(M / 128) * 12, 256, 0, stream>>>(x16, wqkv16, bq, bkv,
                                               q, kv, CDIM, 12, 512, 512, 1024);

  nonlin2_kernel<<<M / 4, 256, 0, stream>>>(q, kv, inv_s, ff);
  kvmat_kernel<<<dim3(32, B * 8), 256, 0, stream>>>(kv, kvm, ksum);
  attn_fz_kernel<<<dim3(N_TOK / 64, B * 8), 256, 0, stream>>>(q, kvm, ksum);
  conv_kernel<<<dim3(8, 8, B * 8 * 2), 256, 0, stream>>>(kv, q, dwc_w, dwc_b);

  // y -> fp16 (kv region is dead after conv), then output projection
  cvt_perm_kernel<<<4096, 256, 0, stream>>>(q, y16, M * 512 / 4);
  gemm_f16<<<(M / 128) * 4, 256, 0, stream>>>(y16, wp16, bp, bp,
                                              (float*)d_out, (float*)d_out, CDIM, 4, 512, 512, 512);
}

// Round 9
// 795.993 us; speedup vs baseline: 2.7794x; 1.2641x over previous
//
#include <hip/hip_runtime.h>
#include <cstdio>

#define N_TOK 16384
#define CDIM  512

typedef unsigned short ushort_t;
typedef _Float16 f16;
typedef __attribute__((ext_vector_type(8))) _Float16 f16x8;
typedef __attribute__((ext_vector_type(4))) _Float16 f16x4;
typedef __attribute__((ext_vector_type(4))) float f32x4;

// ---------------------------------------------------------------- helpers
__device__ __forceinline__ float fast_pow(float x, float p) {
  return __builtin_amdgcn_exp2f(p * __builtin_amdgcn_logf(x));
}
__device__ __forceinline__ void gl_lds16(const void* g, void* l) {
  __builtin_amdgcn_global_load_lds((const __attribute__((address_space(1))) void*)g,
                                   (__attribute__((address_space(3))) void*)l, 16, 0, 0);
}
// permuted fp16 column index (must match cvt_perm_kernel): row r, col k
__device__ __forceinline__ int perm_col(int k, int r) {
  const int kg = k >> 5, c8 = (k >> 3) & 3, e = k & 7;
  return kg * 32 + ((c8 ^ ((r >> 1) & 3)) * 8) + e;
}

// ---------------------------------------------------------------- zero
__global__ void zero_kernel(float* __restrict__ p, int n) {
  int i = blockIdx.x * blockDim.x + threadIdx.x;
  if (i < n) p[i] = 0.f;
}

// ---------------------------------------------------------------- 1/softplus(scale), 512 values
__global__ void sp_kernel(const float* __restrict__ scale, float* __restrict__ inv_s) {
  int i = blockIdx.x * blockDim.x + threadIdx.x;
  if (i < 512) {
    float sc = scale[i];
    float s = (sc > 20.f) ? sc : log1pf(expf(sc));
    inv_s[i] = 1.0f / s;
  }
}

// ---------------------------------------------------------------- fp32 -> fp16, chunk-permuted (512-col rows)
__global__ __launch_bounds__(256) void cvt_perm_kernel(const float* __restrict__ in,
                                                       f16* __restrict__ out, int n4) {
  int i = blockIdx.x * blockDim.x + threadIdx.x;
  const int stride = gridDim.x * blockDim.x;
  for (; i < n4; i += stride) {
    float4 v = ((const float4*)in)[i];
    const int r = i >> 7;
    const int f = i & 127;
    const int kg = f >> 3;
    const int c = (f >> 1) & 3;
    const int e = (f & 1) * 4;
    const int dst = r * 512 + kg * 32 + ((c ^ ((r >> 1) & 3)) * 8) + e;
    f16x4 h;
    h.x = (f16)v.x; h.y = (f16)v.y; h.z = (f16)v.z; h.w = (f16)v.w;
    *(f16x4*)&out[dst] = h;
  }
}

// ---------------------------------------------------------------- fp16 MFMA GEMM, full-DMA
__global__ __launch_bounds__(256, 4) void gemm_f16(const f16* __restrict__ A,
                                                   const f16* __restrict__ Bw,
                                                   const float* __restrict__ b1,
                                                   const float* __restrict__ b2,
                                                   float* __restrict__ C1,
                                                   float* __restrict__ C2,
                                                   const int K, const int nY,
                                                   const int ncol1,
                                                   const int ldc1, const int ldc2) {
  __shared__ __align__(16) f16 As[2][128 * 32];
  __shared__ __align__(16) f16 Bs[2][128 * 32];
  const int t = threadIdx.x;
  const int lane = t & 63;
  const int w = t >> 6;
  const int wr = w >> 1, wc = w & 1;

  const int id = blockIdx.x;
  const int xcd = id & 7;
  const int j = id >> 3;
  const int xpc = (int)(gridDim.x) / (nY * 8);
  const int xloc = j / nY;
  const int y = j - xloc * nY;
  const size_t bm = (size_t)(xcd * xpc + xloc) * 128;
  const int bn = y * 128;

  const int lr = lane & 15;
  const int ksl = lane >> 4;

  f32x4 acc[4][4] = {};

  auto stage = [&](int k0, int buf) {
    const int rsub = lane >> 2;
    const int csub = (lane & 3) * 8;
    const size_t ga = (bm + w * 32 + rsub) * (size_t)K + k0 + csub;
    const size_t gb = ((size_t)(bn + w * 32 + rsub)) * K + k0 + csub;
    gl_lds16(A + ga,                  &As[buf][(w * 32) * 32]);
    gl_lds16(A + ga + 16 * (size_t)K, &As[buf][(w * 32 + 16) * 32]);
    gl_lds16(Bw + gb,                  &Bs[buf][(w * 32) * 32]);
    gl_lds16(Bw + gb + 16 * (size_t)K, &Bs[buf][(w * 32 + 16) * 32]);
  };

  const int nsteps = K >> 5;
  stage(0, 0);
  for (int s = 0; s < nsteps; ++s) {
    const int buf = s & 1;
    __syncthreads();
    f16x8 a[4], b[4];
#pragma unroll
    for (int i = 0; i < 4; ++i) {
      const int rA = wr * 64 + i * 16 + lr;
      a[i] = *(const f16x8*)&As[buf][rA * 32 + ((ksl ^ ((rA >> 1) & 3)) * 8)];
      const int rB = wc * 64 + i * 16 + lr;
      b[i] = *(const f16x8*)&Bs[buf][rB * 32 + ((ksl ^ ((rB >> 1) & 3)) * 8)];
    }
    if (s + 1 < nsteps) stage((s + 1) << 5, buf ^ 1);
#pragma unroll
    for (int mi = 0; mi < 4; ++mi)
#pragma unroll
      for (int ni = 0; ni < 4; ++ni)
        acc[mi][ni] = __builtin_amdgcn_mfma_f32_16x16x32_f16(a[mi], b[ni], acc[mi][ni], 0, 0, 0);
  }

  float* Cb; const float* bb_; int ldc, colbase;
  if (bn < ncol1) { Cb = C1; bb_ = b1; ldc = ldc1; colbase = bn; }
  else            { Cb = C2; bb_ = b2; ldc = ldc2; colbase = bn - ncol1; }
  const int rg = (lane >> 4) << 2;
#pragma unroll
  for (int ni = 0; ni < 4; ++ni) {
    const int col = colbase + wc * 64 + ni * 16 + lr;
    const float bs = bb_[col];
#pragma unroll
    for (int mi = 0; mi < 4; ++mi) {
      float* Cp = Cb + (bm + wr * 64 + mi * 16 + rg) * (size_t)ldc + col;
#pragma unroll
      for (int j2 = 0; j2 < 4; ++j2)
        Cp[(size_t)j2 * ldc] = acc[mi][ni][j2] + bs;
    }
  }
}

// ---------------------------------------------------------------- nonlinearity, wave-per-row (shfl-only)
__global__ __launch_bounds__(256) void nonlin2_kernel(float* __restrict__ q,
                                                      float* __restrict__ kv,
                                                      const float* __restrict__ inv_s,
                                                      const float* __restrict__ ff) {
  const int t = threadIdx.x, lane = t & 63, w = t >> 6;
  const int row = blockIdx.x * 4 + w;
  float* qr = q + (size_t)row * 512 + lane * 8;
  float* kr = kv + (size_t)row * 1024 + lane * 8;

  float qv[8], kval[8], is[8], fv[8];
  *(float4*)&qv[0] = *(const float4*)qr;       *(float4*)&qv[4] = *(const float4*)(qr + 4);
  *(float4*)&kval[0] = *(const float4*)kr;     *(float4*)&kval[4] = *(const float4*)(kr + 4);
  *(float4*)&is[0] = *(const float4*)(inv_s + lane * 8);
  *(float4*)&is[4] = *(const float4*)(inv_s + lane * 8 + 4);
  *(float4*)&fv[0] = *(const float4*)(ff + lane * 8);
  *(float4*)&fv[4] = *(const float4*)(ff + lane * 8 + 4);

  float sq = 0.f, sk = 0.f;
#pragma unroll
  for (int i = 0; i < 8; ++i) {
    qv[i] = (fmaxf(qv[i], 0.f) + 1e-6f) * is[i];
    kval[i] = (fmaxf(kval[i], 0.f) + 1e-6f) * is[i];
    sq += qv[i] * qv[i];
    sk += kval[i] * kval[i];
  }
#pragma unroll
  for (int off = 1; off < 64; off <<= 1) {
    sq += __shfl_xor(sq, off);
    sk += __shfl_xor(sk, off);
  }
  const float qn = sqrtf(sq), kn = sqrtf(sk);

  float pq[8], pk[8], sq2 = 0.f, sk2 = 0.f;
#pragma unroll
  for (int i = 0; i < 8; ++i) {
    pq[i] = fast_pow(qv[i], fv[i]);
    pk[i] = fast_pow(kval[i], fv[i]);
    sq2 += pq[i] * pq[i];
    sk2 += pk[i] * pk[i];
  }
#pragma unroll
  for (int off = 1; off < 64; off <<= 1) {
    sq2 += __shfl_xor(sq2, off);
    sk2 += __shfl_xor(sk2, off);
  }
  const float qs = qn / sqrtf(sq2), ks = kn / sqrtf(sk2);
#pragma unroll
  for (int i = 0; i < 8; ++i) { qv[i] = pq[i] * qs; kval[i] = pk[i] * ks; }
  *(float4*)qr = *(float4*)&qv[0];       *(float4*)(qr + 4) = *(float4*)&qv[4];
  *(float4*)kr = *(float4*)&kval[0];     *(float4*)(kr + 4) = *(float4*)&kval[4];
}

// ---------------------------------------------------------------- kv_mat[bh] = k^T v / N  (+ fused ksum)
__global__ __launch_bounds__(256) void kvmat_kernel(const float* __restrict__ kv,
                                                    float* __restrict__ kvm,
                                                    float* __restrict__ ksum) {
  __shared__ float ks[8][64];
  __shared__ float vs[8][64];
  const int bh = blockIdx.y;
  const int b = bh >> 3, h = bh & 7;
  const int chunk = blockIdx.x;
  const int t = threadIdx.x;
  const int tr = (t >> 4) * 4, tc = (t & 15) * 4;
  float acc[4][4] = {};
  float kacc = 0.f;
  size_t rowbase = (size_t)b * N_TOK + (size_t)chunk * 512;
  for (int it = 0; it < 64; ++it) {
    __syncthreads();
#pragma unroll
    for (int l = 0; l < 4; ++l) {
      int idx = l * 256 + t;
      int ri = idx >> 7, ci = idx & 127;
      size_t g = (rowbase + it * 8 + ri) * 1024 + h * 64;
      if (ci < 64) ks[ri][ci] = kv[g + ci];
      else         vs[ri][ci - 64] = kv[g + 512 + (ci - 64)];
    }
    __syncthreads();
    if (t < 64) {
      float ka = 0.f;
#pragma unroll
      for (int ri = 0; ri < 8; ++ri) ka += ks[ri][t];
      kacc += ka;
    }
#pragma unroll
    for (int ri = 0; ri < 8; ++ri) {
      float a[4], v4[4];
#pragma unroll
      for (int i = 0; i < 4; ++i) a[i] = ks[ri][tr + i];
#pragma unroll
      for (int j = 0; j < 4; ++j) v4[j] = vs[ri][tc + j];
#pragma unroll
      for (int i = 0; i < 4; ++i)
#pragma unroll
        for (int j = 0; j < 4; ++j)
          acc[i][j] = fmaf(a[i], v4[j], acc[i][j]);
    }
  }
  const float scl = 1.0f / (float)N_TOK;
#pragma unroll
  for (int i = 0; i < 4; ++i)
#pragma unroll
    for (int j = 0; j < 4; ++j)
      atomicAdd(&kvm[(size_t)bh * 4096 + (tr + i) * 64 + (tc + j)], acc[i][j] * scl);
  if (t < 64) atomicAdd(&ksum[b * 512 + h * 64 + t], kacc);
}

// ---------------------------------------------------------------- attn with fused z
// use16: write permuted fp16 into y16 (first writer). else: overwrite q fp32.
__global__ __launch_bounds__(256) void attn_fz_kernel(float* __restrict__ q,
                                                      const float* __restrict__ kvm,
                                                      const float* __restrict__ ksum,
                                                      f16* __restrict__ y16,
                                                      const int use16) {
  __shared__ float km[64][64];
  __shared__ float qs[64][64];
  __shared__ float kms[64];
  __shared__ float zl[64];
  const int bh = blockIdx.y;
  const int b = bh >> 3, h = bh & 7;
  const int tok0 = blockIdx.x * 64;
  const int t = threadIdx.x;
  const size_t kvm_base = (size_t)bh * 4096;
  const size_t qbase = ((size_t)b * N_TOK + tok0) * 512 + h * 64;
#pragma unroll
  for (int i = 0; i < 16; ++i) {
    int idx = i * 256 + t;
    km[idx >> 6][idx & 63] = kvm[kvm_base + idx];
    qs[idx >> 6][idx & 63] = q[qbase + (size_t)(idx >> 6) * 512 + (idx & 63)];
  }
  if (t < 64) kms[t] = ksum[b * 512 + h * 64 + t];
  __syncthreads();

  {
    const int tok = t >> 2, dq = (t & 3) * 16;
    float p = 0.f;
#pragma unroll
    for (int i = 0; i < 16; ++i) p += qs[tok][dq + i] * kms[dq + i];
    p += __shfl_xor(p, 1);
    p += __shfl_xor(p, 2);
    if ((t & 3) == 0) zl[tok] = 1.0f / (p * (1.0f / (float)N_TOK) + 1e-6f);
  }
  __syncthreads();

  const int d = t & 63, slot = t >> 6;
  const int col = h * 64 + d;
  for (int i = 0; i < 16; ++i) {
    const int tok = i * 4 + slot;
    float a0 = 0.f, a1 = 0.f, a2 = 0.f, a3 = 0.f;
#pragma unroll
    for (int din = 0; din < 64; din += 4) {
      a0 = fmaf(qs[tok][din + 0], km[din + 0][d], a0);
      a1 = fmaf(qs[tok][din + 1], km[din + 1][d], a1);
      a2 = fmaf(qs[tok][din + 2], km[din + 2][d], a2);
      a3 = fmaf(qs[tok][din + 3], km[din + 3][d], a3);
    }
    const float val = ((a0 + a1) + (a2 + a3)) * zl[tok];
    if (use16) {
      const int r = (int)(b * N_TOK) + tok0 + tok;
      y16[(size_t)r * 512 + perm_col(col, r)] = (f16)val;
    } else {
      q[qbase + (size_t)tok * 512 + d] = val;
    }
  }
}

// ---------------------------------------------------------------- depthwise 5x5 conv on v
// 16x16 pixels x 16 channels per block; float4 staging; vt 25.6 KB.
// use16: fused fp16 RMW into permuted y16. else: fp32 += into y32.
__global__ __launch_bounds__(256, 4) void conv_kernel(const float* __restrict__ kv,
                                                      float* __restrict__ y32,
                                                      f16* __restrict__ y16,
                                                      const int use16,
                                                      const float* __restrict__ wconv,
                                                      const float* __restrict__ bconv) {
  __shared__ float vt[20 * 20 * 16];
  const int zidx = blockIdx.z;          // bh*4 + channel-quarter
  const int bh = zidx >> 2, cq = zidx & 3;
  const int b = bh >> 3, h = bh & 7;
  const int c0 = cq * 16;
  const int tx0 = blockIdx.x * 16, ty0 = blockIdx.y * 16;
  const int t = threadIdx.x;
  const size_t vrow = (size_t)b * N_TOK * 1024 + 512 + h * 64 + c0;
  // stage halo: 400 px x 16 ch = 1600 float4
#pragma unroll
  for (int i = 0; i < 7; ++i) {
    const int idx = i * 256 + t;
    if (idx < 1600) {
      const int pix = idx >> 2, c4 = (idx & 3) * 4;
      const int lx = pix % 20, ly = pix / 20;
      const int gx = tx0 + lx - 2, gy = ty0 + ly - 2;
      float4 val = make_float4(0.f, 0.f, 0.f, 0.f);
      if ((unsigned)gx < 128u && (unsigned)gy < 128u)
        val = *(const float4*)&kv[vrow + (size_t)(gy * 128 + gx) * 1024 + c4];
      *(float4*)&vt[pix * 16 + c4] = val;
    }
  }
  const int c = t & 15;
  const int dd = c0 + c;                // channel within head 0..63
  float w[25];
#pragma unroll
  for (int k = 0; k < 25; ++k) w[k] = wconv[dd * 25 + k];
  const float bb = bconv[dd];
  __syncthreads();
  const int slot = t >> 4;              // 16 pixel slots
  const int col = h * 64 + dd;
  for (int i = 0; i < 16; ++i) {
    const int pix = i * 16 + slot;
    const int px = pix & 15, py = pix >> 4;
    float acc = bb;
#pragma unroll
    for (int ky = 0; ky < 5; ++ky)
#pragma unroll
      for (int kx = 0; kx < 5; ++kx)
        acc = fmaf(w[ky * 5 + kx], vt[((py + ky) * 20 + (px + kx)) * 16 + c], acc);
    const int r = (int)(b * N_TOK) + (ty0 + py) * 128 + (tx0 + px);
    if (use16) {
      f16* p = &y16[(size_t)r * 512 + perm_col(col, r)];
      *p = (f16)((float)*p + acc);
    } else {
      y32[(size_t)r * 512 + col] += acc;
    }
  }
}

// ---------------------------------------------------------------- launch
extern "C" void kernel_launch(void* const* d_in, const int* in_sizes, int n_in,
                              void* d_out, int out_size, void* d_ws, size_t ws_size,
                              hipStream_t stream) {
  (void)n_in; (void)out_size;
  const float* x     = (const float*)d_in[0];
  const float* Wq    = (const float*)d_in[1];
  const float* bq    = (const float*)d_in[2];
  const float* Wkv   = (const float*)d_in[3];
  const float* bkv   = (const float*)d_in[4];
  const float* Wp    = (const float*)d_in[5];
  const float* bp    = (const float*)d_in[6];
  const float* ff    = (const float*)d_in[7];
  const float* scale = (const float*)d_in[8];
  const float* dwc_w = (const float*)d_in[9];
  const float* dwc_b = (const float*)d_in[10];

  const int B = in_sizes[0] / (N_TOK * CDIM);   // 4
  const int M = B * N_TOK;                      // 65536

  // base workspace layout: round-1 known-good 405.3 MB footprint
  float* q    = (float*)d_ws;                          // M x 512
  float* kv   = q + (size_t)M * 512;                   // M x 1024 (k | v)
  float* ksum = kv + (size_t)M * 1024;                 // B x 512
  float* kvm  = ksum + (size_t)B * 512;                // 32 x 64 x 64
  float* z    = kvm + (size_t)B * 8 * 4096;            // 2 MB scratch

  size_t need = ((size_t)M * 1536 + (size_t)B * 512 + (size_t)B * 8 * 4096 +
                 (size_t)B * 8 * N_TOK) * sizeof(float);
  if (ws_size < need) {
    fprintf(stderr, "kernel_launch: ws too small (%zu < %zu)\n", ws_size, need);
    return;
  }
  // optional +64 MB region for direct-fp16 y (fused cvt); fallback-gated.
  const size_t need16 = need + (size_t)M * 512 * sizeof(f16);
  const int use16 = (ws_size >= need16) ? 1 : 0;
  f16* y16 = use16 ? (f16*)((char*)d_ws + need) : (f16*)kv;   // fallback: kv region (dead after conv)

  // scratch carve-outs:
  //  - d_out head (free until final GEMM): x16 (64 MB) + wqkv16 (1.5 MB)
  //  - z region: wp16 (0.5 MB) + inv_s (2 KB)
  f16* x16    = (f16*)d_out;
  f16* wqkv16 = x16 + (size_t)M * 512;
  f16* wp16   = (f16*)z;
  float* inv_s = z + 131072;

  const int nsmall = B * 512 + B * 8 * 4096;
  zero_kernel<<<(nsmall + 255) / 256, 256, 0, stream>>>(ksum, nsmall);
  sp_kernel<<<2, 256, 0, stream>>>(scale, inv_s);
  cvt_perm_kernel<<<4096, 256, 0, stream>>>(x, x16, M * 512 / 4);
  cvt_perm_kernel<<<256, 256, 0, stream>>>(Wq, wqkv16, 512 * 512 / 4);
  cvt_perm_kernel<<<512, 256, 0, stream>>>(Wkv, wqkv16 + 512 * 512, 1024 * 512 / 4);
  cvt_perm_kernel<<<256, 256, 0, stream>>>(Wp, wp16, 512 * 512 / 4);

  // fused q+kv projection: Nout = 1536; cols <512 -> q (ldc 512), else kv (ldc 1024)
  gemm_f16<<<(M / 128) * 12, 256, 0, stream>>>(x16, wqkv16, bq, bkv,
                                               q, kv, CDIM, 12, 512, 512, 1024);

  nonlin2_kernel<<<M / 4, 256, 0, stream>>>(q, kv, inv_s, ff);
  kvmat_kernel<<<dim3(32, B * 8), 256, 0, stream>>>(kv, kvm, ksum);
  attn_fz_kernel<<<dim3(N_TOK / 64, B * 8), 256, 0, stream>>>(q, kvm, ksum, y16, use16);
  conv_kernel<<<dim3(8, 8, B * 8 * 4), 256, 0, stream>>>(kv, q, y16, use16, dwc_w, dwc_b);

  if (!use16)   // fallback: y (in q) -> permuted fp16 in dead kv region
    cvt_perm_kernel<<<4096, 256, 0, stream>>>(q, y16, M * 512 / 4);

  gemm_f16<<<(M / 128) * 4, 256, 0, stream>>>(y16, wp16, bp, bp,
                                              (float*)d_out, (float*)d_out, CDIM, 4, 512, 512, 512);
}

// Round 10
// 707.164 us; speedup vs baseline: 3.1285x; 1.1256x over previous
//
#include <hip/hip_runtime.h>
#include <cstdio>

#define N_TOK 16384
#define CDIM  512

typedef unsigned short ushort_t;
typedef _Float16 f16;
typedef __attribute__((ext_vector_type(8))) _Float16 f16x8;
typedef __attribute__((ext_vector_type(4))) _Float16 f16x4;
typedef __attribute__((ext_vector_type(4))) float f32x4;

// ---------------------------------------------------------------- helpers
__device__ __forceinline__ float fast_pow(float x, float p) {
  return __builtin_amdgcn_exp2f(p * __builtin_amdgcn_logf(x));
}
__device__ __forceinline__ void gl_lds16(const void* g, void* l) {
  __builtin_amdgcn_global_load_lds((const __attribute__((address_space(1))) void*)g,
                                   (__attribute__((address_space(3))) void*)l, 16, 0, 0);
}
// permuted fp16 column index (must match cvt_perm_kernel): row r, col k
__device__ __forceinline__ int perm_col(int k, int r) {
  const int kg = k >> 5, c8 = (k >> 3) & 3, e = k & 7;
  return kg * 32 + ((c8 ^ ((r >> 1) & 3)) * 8) + e;
}

// ---------------------------------------------------------------- zero
__global__ void zero_kernel(float* __restrict__ p, int n) {
  int i = blockIdx.x * blockDim.x + threadIdx.x;
  if (i < n) p[i] = 0.f;
}

// ---------------------------------------------------------------- 1/softplus(scale), 512 values
__global__ void sp_kernel(const float* __restrict__ scale, float* __restrict__ inv_s) {
  int i = blockIdx.x * blockDim.x + threadIdx.x;
  if (i < 512) {
    float sc = scale[i];
    float s = (sc > 20.f) ? sc : log1pf(expf(sc));
    inv_s[i] = 1.0f / s;
  }
}

// ---------------------------------------------------------------- fp32 -> fp16, chunk-permuted (512-col rows)
__global__ __launch_bounds__(256) void cvt_perm_kernel(const float* __restrict__ in,
                                                       f16* __restrict__ out, int n4) {
  int i = blockIdx.x * blockDim.x + threadIdx.x;
  const int stride = gridDim.x * blockDim.x;
  for (; i < n4; i += stride) {
    float4 v = ((const float4*)in)[i];
    const int r = i >> 7;
    const int f = i & 127;
    const int kg = f >> 3;
    const int c = (f >> 1) & 3;
    const int e = (f & 1) * 4;
    const int dst = r * 512 + kg * 32 + ((c ^ ((r >> 1) & 3)) * 8) + e;
    f16x4 h;
    h.x = (f16)v.x; h.y = (f16)v.y; h.z = (f16)v.z; h.w = (f16)v.w;
    *(f16x4*)&out[dst] = h;
  }
}

// ---------------------------------------------------------------- fp16 MFMA GEMM, full-DMA
__global__ __launch_bounds__(256, 4) void gemm_f16(const f16* __restrict__ A,
                                                   const f16* __restrict__ Bw,
                                                   const float* __restrict__ b1,
                                                   const float* __restrict__ b2,
                                                   float* __restrict__ C1,
                                                   float* __restrict__ C2,
                                                   const int K, const int nY,
                                                   const int ncol1,
                                                   const int ldc1, const int ldc2) {
  __shared__ __align__(16) f16 As[2][128 * 32];
  __shared__ __align__(16) f16 Bs[2][128 * 32];
  const int t = threadIdx.x;
  const int lane = t & 63;
  const int w = t >> 6;
  const int wr = w >> 1, wc = w & 1;

  const int id = blockIdx.x;
  const int xcd = id & 7;
  const int j = id >> 3;
  const int xpc = (int)(gridDim.x) / (nY * 8);
  const int xloc = j / nY;
  const int y = j - xloc * nY;
  const size_t bm = (size_t)(xcd * xpc + xloc) * 128;
  const int bn = y * 128;

  const int lr = lane & 15;
  const int ksl = lane >> 4;

  f32x4 acc[4][4] = {};

  auto stage = [&](int k0, int buf) {
    const int rsub = lane >> 2;
    const int csub = (lane & 3) * 8;
    const size_t ga = (bm + w * 32 + rsub) * (size_t)K + k0 + csub;
    const size_t gb = ((size_t)(bn + w * 32 + rsub)) * K + k0 + csub;
    gl_lds16(A + ga,                  &As[buf][(w * 32) * 32]);
    gl_lds16(A + ga + 16 * (size_t)K, &As[buf][(w * 32 + 16) * 32]);
    gl_lds16(Bw + gb,                  &Bs[buf][(w * 32) * 32]);
    gl_lds16(Bw + gb + 16 * (size_t)K, &Bs[buf][(w * 32 + 16) * 32]);
  };

  const int nsteps = K >> 5;
  stage(0, 0);
  for (int s = 0; s < nsteps; ++s) {
    const int buf = s & 1;
    __syncthreads();
    f16x8 a[4], b[4];
#pragma unroll
    for (int i = 0; i < 4; ++i) {
      const int rA = wr * 64 + i * 16 + lr;
      a[i] = *(const f16x8*)&As[buf][rA * 32 + ((ksl ^ ((rA >> 1) & 3)) * 8)];
      const int rB = wc * 64 + i * 16 + lr;
      b[i] = *(const f16x8*)&Bs[buf][rB * 32 + ((ksl ^ ((rB >> 1) & 3)) * 8)];
    }
    if (s + 1 < nsteps) stage((s + 1) << 5, buf ^ 1);
#pragma unroll
    for (int mi = 0; mi < 4; ++mi)
#pragma unroll
      for (int ni = 0; ni < 4; ++ni)
        acc[mi][ni] = __builtin_amdgcn_mfma_f32_16x16x32_f16(a[mi], b[ni], acc[mi][ni], 0, 0, 0);
  }

  float* Cb; const float* bb_; int ldc, colbase;
  if (bn < ncol1) { Cb = C1; bb_ = b1; ldc = ldc1; colbase = bn; }
  else            { Cb = C2; bb_ = b2; ldc = ldc2; colbase = bn - ncol1; }
  const int rg = (lane >> 4) << 2;
#pragma unroll
  for (int ni = 0; ni < 4; ++ni) {
    const int col = colbase + wc * 64 + ni * 16 + lr;
    const float bs = bb_[col];
#pragma unroll
    for (int mi = 0; mi < 4; ++mi) {
      float* Cp = Cb + (bm + wr * 64 + mi * 16 + rg) * (size_t)ldc + col;
#pragma unroll
      for (int j2 = 0; j2 < 4; ++j2)
        Cp[(size_t)j2 * ldc] = acc[mi][ni][j2] + bs;
    }
  }
}

// ---------------------------------------------------------------- nonlinearity, wave-per-row (shfl-only)
__global__ __launch_bounds__(256) void nonlin2_kernel(float* __restrict__ q,
                                                      float* __restrict__ kv,
                                                      const float* __restrict__ inv_s,
                                                      const float* __restrict__ ff) {
  const int t = threadIdx.x, lane = t & 63, w = t >> 6;
  const int row = blockIdx.x * 4 + w;
  float* qr = q + (size_t)row * 512 + lane * 8;
  float* kr = kv + (size_t)row * 1024 + lane * 8;

  float qv[8], kval[8], is[8], fv[8];
  *(float4*)&qv[0] = *(const float4*)qr;       *(float4*)&qv[4] = *(const float4*)(qr + 4);
  *(float4*)&kval[0] = *(const float4*)kr;     *(float4*)&kval[4] = *(const float4*)(kr + 4);
  *(float4*)&is[0] = *(const float4*)(inv_s + lane * 8);
  *(float4*)&is[4] = *(const float4*)(inv_s + lane * 8 + 4);
  *(float4*)&fv[0] = *(const float4*)(ff + lane * 8);
  *(float4*)&fv[4] = *(const float4*)(ff + lane * 8 + 4);

  float sq = 0.f, sk = 0.f;
#pragma unroll
  for (int i = 0; i < 8; ++i) {
    qv[i] = (fmaxf(qv[i], 0.f) + 1e-6f) * is[i];
    kval[i] = (fmaxf(kval[i], 0.f) + 1e-6f) * is[i];
    sq += qv[i] * qv[i];
    sk += kval[i] * kval[i];
  }
#pragma unroll
  for (int off = 1; off < 64; off <<= 1) {
    sq += __shfl_xor(sq, off);
    sk += __shfl_xor(sk, off);
  }
  const float qn = sqrtf(sq), kn = sqrtf(sk);

  float pq[8], pk[8], sq2 = 0.f, sk2 = 0.f;
#pragma unroll
  for (int i = 0; i < 8; ++i) {
    pq[i] = fast_pow(qv[i], fv[i]);
    pk[i] = fast_pow(kval[i], fv[i]);
    sq2 += pq[i] * pq[i];
    sk2 += pk[i] * pk[i];
  }
#pragma unroll
  for (int off = 1; off < 64; off <<= 1) {
    sq2 += __shfl_xor(sq2, off);
    sk2 += __shfl_xor(sk2, off);
  }
  const float qs = qn / sqrtf(sq2), ks = kn / sqrtf(sk2);
#pragma unroll
  for (int i = 0; i < 8; ++i) { qv[i] = pq[i] * qs; kval[i] = pk[i] * ks; }
  *(float4*)qr = *(float4*)&qv[0];       *(float4*)(qr + 4) = *(float4*)&qv[4];
  *(float4*)kr = *(float4*)&kval[0];     *(float4*)(kr + 4) = *(float4*)&kval[4];
}

// ---------------------------------------------------------------- kv_mat[bh] = k^T v / N  (+ fused ksum)
// Barrier-free main loop: each wave owns 128 rows; lane l loads k[row][l], v[row][l]
// (coalesced); __shfl broadcasts feed an 8x8 per-lane outer-product accumulator
// (interleaved mapping: rows r0+8i, cols c0+8j). Cross-wave reduce via padded LDS.
__global__ __launch_bounds__(256, 4) void kvmat2_kernel(const float* __restrict__ kv,
                                                        float* __restrict__ kvm,
                                                        float* __restrict__ ksum) {
  __shared__ float tile[64 * 66];   // stride 66 -> <=4-way on reduce (free-ish)
  const int bh = blockIdx.y;
  const int b = bh >> 3, h = bh & 7;
  const int chunk = blockIdx.x;     // 0..31 (512 rows each)
  const int t = threadIdx.x, lane = t & 63, w = t >> 6;
  const int r0 = lane >> 3;         // owns rows r0+8i
  const int c0 = lane & 7;          // owns cols c0+8j
  float acc[8][8] = {};
  float kacc = 0.f;
  const size_t base = ((size_t)b * N_TOK + (size_t)chunk * 512 + w * 128) * 1024 + h * 64;
  const float* kp = kv + base + lane;
  const float* vp = kv + base + 512 + lane;

  float kcur = kp[0], vcur = vp[0];
  auto body = [&](float kc, float vc) {
    kacc += kc;
    float kk[8], vv[8];
#pragma unroll
    for (int i = 0; i < 8; ++i) {
      kk[i] = __shfl(kc, r0 + i * 8);
      vv[i] = __shfl(vc, c0 + i * 8);
    }
#pragma unroll
    for (int i = 0; i < 8; ++i)
#pragma unroll
      for (int j = 0; j < 8; ++j)
        acc[i][j] = fmaf(kk[i], vv[j], acc[i][j]);
  };
  for (int r = 0; r < 127; ++r) {
    const float knx = kp[(size_t)(r + 1) * 1024];
    const float vnx = vp[(size_t)(r + 1) * 1024];
    body(kcur, vcur);
    kcur = knx; vcur = vnx;
  }
  body(kcur, vcur);

  atomicAdd(&ksum[b * 512 + h * 64 + lane], kacc);   // lane == k channel

  // sequential cross-wave reduction
  for (int ww = 0; ww < 4; ++ww) {
    if (w == ww) {
#pragma unroll
      for (int i = 0; i < 8; ++i)
#pragma unroll
        for (int j = 0; j < 8; ++j) {
          const int a = (r0 + i * 8) * 66 + c0 + j * 8;
          tile[a] = (ww == 0) ? acc[i][j] : tile[a] + acc[i][j];
        }
    }
    __syncthreads();
  }
  const float scl = 1.0f / (float)N_TOK;
#pragma unroll
  for (int i = 0; i < 16; ++i) {
    const int idx = i * 256 + t;           // 0..4095
    const int rr = idx >> 6, cc = idx & 63;
    atomicAdd(&kvm[(size_t)bh * 4096 + idx], tile[rr * 66 + cc] * scl);
  }
}

// ---------------------------------------------------------------- attn with fused z
__global__ __launch_bounds__(256) void attn_fz_kernel(float* __restrict__ q,
                                                      const float* __restrict__ kvm,
                                                      const float* __restrict__ ksum,
                                                      f16* __restrict__ y16,
                                                      const int use16) {
  __shared__ float km[64][64];
  __shared__ float qs[64][64];
  __shared__ float kms[64];
  __shared__ float zl[64];
  const int bh = blockIdx.y;
  const int b = bh >> 3, h = bh & 7;
  const int tok0 = blockIdx.x * 64;
  const int t = threadIdx.x;
  const size_t kvm_base = (size_t)bh * 4096;
  const size_t qbase = ((size_t)b * N_TOK + tok0) * 512 + h * 64;
#pragma unroll
  for (int i = 0; i < 16; ++i) {
    int idx = i * 256 + t;
    km[idx >> 6][idx & 63] = kvm[kvm_base + idx];
    qs[idx >> 6][idx & 63] = q[qbase + (size_t)(idx >> 6) * 512 + (idx & 63)];
  }
  if (t < 64) kms[t] = ksum[b * 512 + h * 64 + t];
  __syncthreads();

  {
    const int tok = t >> 2, dq = (t & 3) * 16;
    float p = 0.f;
#pragma unroll
    for (int i = 0; i < 16; ++i) p += qs[tok][dq + i] * kms[dq + i];
    p += __shfl_xor(p, 1);
    p += __shfl_xor(p, 2);
    if ((t & 3) == 0) zl[tok] = 1.0f / (p * (1.0f / (float)N_TOK) + 1e-6f);
  }
  __syncthreads();

  const int d = t & 63, slot = t >> 6;
  const int col = h * 64 + d;
  for (int i = 0; i < 16; ++i) {
    const int tok = i * 4 + slot;
    float a0 = 0.f, a1 = 0.f, a2 = 0.f, a3 = 0.f;
#pragma unroll
    for (int din = 0; din < 64; din += 4) {
      a0 = fmaf(qs[tok][din + 0], km[din + 0][d], a0);
      a1 = fmaf(qs[tok][din + 1], km[din + 1][d], a1);
      a2 = fmaf(qs[tok][din + 2], km[din + 2][d], a2);
      a3 = fmaf(qs[tok][din + 3], km[din + 3][d], a3);
    }
    const float val = ((a0 + a1) + (a2 + a3)) * zl[tok];
    if (use16) {
      const int r = (int)(b * N_TOK) + tok0 + tok;
      y16[(size_t)r * 512 + perm_col(col, r)] = (f16)val;
    } else {
      q[qbase + (size_t)tok * 512 + d] = val;
    }
  }
}

// ---------------------------------------------------------------- depthwise 5x5 conv on v
__global__ __launch_bounds__(256, 4) void conv_kernel(const float* __restrict__ kv,
                                                      float* __restrict__ y32,
                                                      f16* __restrict__ y16,
                                                      const int use16,
                                                      const float* __restrict__ wconv,
                                                      const float* __restrict__ bconv) {
  __shared__ float vt[20 * 20 * 16];
  const int zidx = blockIdx.z;
  const int bh = zidx >> 2, cq = zidx & 3;
  const int b = bh >> 3, h = bh & 7;
  const int c0 = cq * 16;
  const int tx0 = blockIdx.x * 16, ty0 = blockIdx.y * 16;
  const int t = threadIdx.x;
  const size_t vrow = (size_t)b * N_TOK * 1024 + 512 + h * 64 + c0;
#pragma unroll
  for (int i = 0; i < 7; ++i) {
    const int idx = i * 256 + t;
    if (idx < 1600) {
      const int pix = idx >> 2, c4 = (idx & 3) * 4;
      const int lx = pix % 20, ly = pix / 20;
      const int gx = tx0 + lx - 2, gy = ty0 + ly - 2;
      float4 val = make_float4(0.f, 0.f, 0.f, 0.f);
      if ((unsigned)gx < 128u && (unsigned)gy < 128u)
        val = *(const float4*)&kv[vrow + (size_t)(gy * 128 + gx) * 1024 + c4];
      *(float4*)&vt[pix * 16 + c4] = val;
    }
  }
  const int c = t & 15;
  const int dd = c0 + c;
  float w[25];
#pragma unroll
  for (int k = 0; k < 25; ++k) w[k] = wconv[dd * 25 + k];
  const float bb = bconv[dd];
  __syncthreads();
  const int slot = t >> 4;
  const int col = h * 64 + dd;
  for (int i = 0; i < 16; ++i) {
    const int pix = i * 16 + slot;
    const int px = pix & 15, py = pix >> 4;
    float acc = bb;
#pragma unroll
    for (int ky = 0; ky < 5; ++ky)
#pragma unroll
      for (int kx = 0; kx < 5; ++kx)
        acc = fmaf(w[ky * 5 + kx], vt[((py + ky) * 20 + (px + kx)) * 16 + c], acc);
    const int r = (int)(b * N_TOK) + (ty0 + py) * 128 + (tx0 + px);
    if (use16) {
      f16* p = &y16[(size_t)r * 512 + perm_col(col, r)];
      *p = (f16)((float)*p + acc);
    } else {
      y32[(size_t)r * 512 + col] += acc;
    }
  }
}

// ---------------------------------------------------------------- launch
extern "C" void kernel_launch(void* const* d_in, const int* in_sizes, int n_in,
                              void* d_out, int out_size, void* d_ws, size_t ws_size,
                              hipStream_t stream) {
  (void)n_in; (void)out_size;
  const float* x     = (const float*)d_in[0];
  const float* Wq    = (const float*)d_in[1];
  const float* bq    = (const float*)d_in[2];
  const float* Wkv   = (const float*)d_in[3];
  const float* bkv   = (const float*)d_in[4];
  const float* Wp    = (const float*)d_in[5];
  const float* bp    = (const float*)d_in[6];
  const float* ff    = (const float*)d_in[7];
  const float* scale = (const float*)d_in[8];
  const float* dwc_w = (const float*)d_in[9];
  const float* dwc_b = (const float*)d_in[10];

  const int B = in_sizes[0] / (N_TOK * CDIM);   // 4
  const int M = B * N_TOK;                      // 65536

  // base workspace layout: round-1 known-good 405.3 MB footprint
  float* q    = (float*)d_ws;                          // M x 512
  float* kv   = q + (size_t)M * 512;                   // M x 1024 (k | v)
  float* ksum = kv + (size_t)M * 1024;                 // B x 512
  float* kvm  = ksum + (size_t)B * 512;                // 32 x 64 x 64
  float* z    = kvm + (size_t)B * 8 * 4096;            // 2 MB scratch

  size_t need = ((size_t)M * 1536 + (size_t)B * 512 + (size_t)B * 8 * 4096 +
                 (size_t)B * 8 * N_TOK) * sizeof(float);
  if (ws_size < need) {
    fprintf(stderr, "kernel_launch: ws too small (%zu < %zu)\n", ws_size, need);
    return;
  }
  const size_t need16 = need + (size_t)M * 512 * sizeof(f16);
  const int use16 = (ws_size >= need16) ? 1 : 0;
  f16* y16 = use16 ? (f16*)((char*)d_ws + need) : (f16*)kv;

  f16* x16    = (f16*)d_out;
  f16* wqkv16 = x16 + (size_t)M * 512;
  f16* wp16   = (f16*)z;
  float* inv_s = z + 131072;

  const int nsmall = B * 512 + B * 8 * 4096;
  zero_kernel<<<(nsmall + 255) / 256, 256, 0, stream>>>(ksum, nsmall);
  sp_kernel<<<2, 256, 0, stream>>>(scale, inv_s);
  cvt_perm_kernel<<<4096, 256, 0, stream>>>(x, x16, M * 512 / 4);
  cvt_perm_kernel<<<256, 256, 0, stream>>>(Wq, wqkv16, 512 * 512 / 4);
  cvt_perm_kernel<<<512, 256, 0, stream>>>(Wkv, wqkv16 + 512 * 512, 1024 * 512 / 4);
  cvt_perm_kernel<<<256, 256, 0, stream>>>(Wp, wp16, 512 * 512 / 4);

  // fused q+kv projection: Nout = 1536; cols <512 -> q (ldc 512), else kv (ldc 1024)
  gemm_f16<<<(M / 128) * 12, 256, 0, stream>>>(x16, wqkv16, bq, bkv,
                                               q, kv, CDIM, 12, 512, 512, 1024);

  nonlin2_kernel<<<M / 4, 256, 0, stream>>>(q, kv, inv_s, ff);
  kvmat2_kernel<<<dim3(32, B * 8), 256, 0, stream>>>(kv, kvm, ksum);
  attn_fz_kernel<<<dim3(N_TOK / 64, B * 8), 256, 0, stream>>>(q, kvm, ksum, y16, use16);
  conv_kernel<<<dim3(8, 8, B * 8 * 4), 256, 0, stream>>>(kv, q, y16, use16, dwc_w, dwc_b);

  if (!use16)
    cvt_perm_kernel<<<4096, 256, 0, stream>>>(q, y16, M * 512 / 4);

  gemm_f16<<<(M / 128) * 4, 256, 0, stream>>>(y16, wp16, bp, bp,
                                              (float*)d_out, (float*)d_out, CDIM, 4, 512, 512, 512);
}

// Round 12
// 601.482 us; speedup vs baseline: 3.6782x; 1.1757x over previous
//
#include <hip/hip_runtime.h>
#include <cstdio>

#define N_TOK 16384
#define CDIM  512

typedef unsigned short ushort_t;
typedef _Float16 f16;
typedef __attribute__((ext_vector_type(8))) _Float16 f16x8;
typedef __attribute__((ext_vector_type(4))) _Float16 f16x4;
typedef __attribute__((ext_vector_type(4))) float f32x4;

// ---------------------------------------------------------------- helpers
__device__ __forceinline__ float fast_pow(float x, float p) {
  return __builtin_amdgcn_exp2f(p * __builtin_amdgcn_logf(x));
}
__device__ __forceinline__ void gl_lds16(const void* g, void* l) {
  __builtin_amdgcn_global_load_lds((const __attribute__((address_space(1))) void*)g,
                                   (__attribute__((address_space(3))) void*)l, 16, 0, 0);
}
// permuted fp16 column index (must match cvt_perm_kernel): row r, col k
__device__ __forceinline__ int perm_col(int k, int r) {
  const int kg = k >> 5, c8 = (k >> 3) & 3, e = k & 7;
  return kg * 32 + ((c8 ^ ((r >> 1) & 3)) * 8) + e;
}

// ---------------------------------------------------------------- zero
__global__ void zero_kernel(float* __restrict__ p, int n) {
  int i = blockIdx.x * blockDim.x + threadIdx.x;
  if (i < n) p[i] = 0.f;
}

// ---------------------------------------------------------------- 1/softplus(scale), 512 values
__global__ void sp_kernel(const float* __restrict__ scale, float* __restrict__ inv_s) {
  int i = blockIdx.x * blockDim.x + threadIdx.x;
  if (i < 512) {
    float sc = scale[i];
    float s = (sc > 20.f) ? sc : log1pf(expf(sc));
    inv_s[i] = 1.0f / s;
  }
}

// ---------------------------------------------------------------- fp32 -> fp16, chunk-permuted (512-col rows)
__global__ __launch_bounds__(256) void cvt_perm_kernel(const float* __restrict__ in,
                                                       f16* __restrict__ out, int n4) {
  int i = blockIdx.x * blockDim.x + threadIdx.x;
  const int stride = gridDim.x * blockDim.x;
  for (; i < n4; i += stride) {
    float4 v = ((const float4*)in)[i];
    const int r = i >> 7;
    const int f = i & 127;
    const int kg = f >> 3;
    const int c = (f >> 1) & 3;
    const int e = (f & 1) * 4;
    const int dst = r * 512 + kg * 32 + ((c ^ ((r >> 1) & 3)) * 8) + e;
    f16x4 h;
    h.x = (f16)v.x; h.y = (f16)v.y; h.z = (f16)v.z; h.w = (f16)v.w;
    *(f16x4*)&out[dst] = h;
  }
}

// ---------------------------------------------------------------- fp16 MFMA GEMM, full-DMA
// OUT16=1: write fp16 to C16 (ldc cols), bias-added, coalesced via LDS restage.
// OUT16=0: write fp32 to C32 directly.
template <int OUT16>
__global__ __launch_bounds__(256, 4) void gemm_f16(const f16* __restrict__ A,
                                                   const f16* __restrict__ Bw,
                                                   const float* __restrict__ b1,
                                                   const float* __restrict__ b2,
                                                   float* __restrict__ C32,
                                                   f16* __restrict__ C16,
                                                   const int K, const int nY,
                                                   const int ncol1, const int ldc) {
  __shared__ __align__(16) f16 SMEM[16896];    // 33.8 KB: staging (32 KB) / epilogue restage
  const int t = threadIdx.x;
  const int lane = t & 63;
  const int w = t >> 6;
  const int wr = w >> 1, wc = w & 1;

  const int id = blockIdx.x;
  const int xcd = id & 7;
  const int j = id >> 3;
  const int xpc = (int)(gridDim.x) / (nY * 8);
  const int xloc = j / nY;
  const int y = j - xloc * nY;
  const size_t bm = (size_t)(xcd * xpc + xloc) * 128;
  const int bn = y * 128;

  const int lr = lane & 15;
  const int ksl = lane >> 4;

  f32x4 acc[4][4] = {};

  // buffer layout: A0 @0, A1 @4096, B0 @8192, B1 @12288 (f16 elements)
  auto stage = [&](int k0, int buf) {
    const int rsub = lane >> 2;
    const int csub = (lane & 3) * 8;
    const size_t ga = (bm + w * 32 + rsub) * (size_t)K + k0 + csub;
    const size_t gb = ((size_t)(bn + w * 32 + rsub)) * K + k0 + csub;
    f16* Ab = SMEM + buf * 4096;
    f16* Bb = SMEM + 8192 + buf * 4096;
    gl_lds16(A + ga,                   Ab + (w * 32) * 32);
    gl_lds16(A + ga + 16 * (size_t)K,  Ab + (w * 32 + 16) * 32);
    gl_lds16(Bw + gb,                  Bb + (w * 32) * 32);
    gl_lds16(Bw + gb + 16 * (size_t)K, Bb + (w * 32 + 16) * 32);
  };

  const int nsteps = K >> 5;
  stage(0, 0);
  for (int s = 0; s < nsteps; ++s) {
    const int buf = s & 1;
    __syncthreads();
    const f16* Ab = SMEM + buf * 4096;
    const f16* Bb = SMEM + 8192 + buf * 4096;
    f16x8 a[4], b[4];
#pragma unroll
    for (int i = 0; i < 4; ++i) {
      const int rA = wr * 64 + i * 16 + lr;
      a[i] = *(const f16x8*)&Ab[rA * 32 + ((ksl ^ ((rA >> 1) & 3)) * 8)];
      const int rB = wc * 64 + i * 16 + lr;
      b[i] = *(const f16x8*)&Bb[rB * 32 + ((ksl ^ ((rB >> 1) & 3)) * 8)];
    }
    if (s + 1 < nsteps) stage((s + 1) << 5, buf ^ 1);
#pragma unroll
    for (int mi = 0; mi < 4; ++mi)
#pragma unroll
      for (int ni = 0; ni < 4; ++ni)
        acc[mi][ni] = __builtin_amdgcn_mfma_f32_16x16x32_f16(a[mi], b[ni], acc[mi][ni], 0, 0, 0);
  }

  // epilogue: C/D layout col=lane&15, row=(lane>>4)*4+reg (m89-verified)
  const int rg = (lane >> 4) << 2;
  if (OUT16) {
    // restage through LDS (132-padded rows) -> coalesced f16x8 global stores
    __syncthreads();
#pragma unroll
    for (int ni = 0; ni < 4; ++ni) {
      const int cl = wc * 64 + ni * 16 + lr;
      const int cg = bn + cl;
      const float bs = (cg < ncol1) ? b1[cg] : b2[cg - ncol1];
#pragma unroll
      for (int mi = 0; mi < 4; ++mi)
#pragma unroll
        for (int j2 = 0; j2 < 4; ++j2)
          SMEM[(wr * 64 + mi * 16 + rg + j2) * 132 + cl] = (f16)(acc[mi][ni][j2] + bs);
    }
    __syncthreads();
#pragma unroll
    for (int i = 0; i < 8; ++i) {
      const int idx = i * 256 + t;          // 2048 chunks
      const int rl = idx >> 4, ch = (idx & 15) * 8;
      *(f16x8*)&C16[(bm + rl) * (size_t)ldc + bn + ch] = *(const f16x8*)&SMEM[rl * 132 + ch];
    }
  } else {
#pragma unroll
    for (int ni = 0; ni < 4; ++ni) {
      const int col = bn + wc * 64 + ni * 16 + lr;
      const float bs = (col < ncol1) ? b1[col] : b2[col - ncol1];
#pragma unroll
      for (int mi = 0; mi < 4; ++mi) {
        float* Cp = C32 + (bm + wr * 64 + mi * 16 + rg) * (size_t)ldc + col;
#pragma unroll
        for (int j2 = 0; j2 < 4; ++j2)
          Cp[(size_t)j2 * ldc] = acc[mi][ni][j2] + bs;
      }
    }
  }
}

// ---------------------------------------------------------------- nonlinearity, wave-per-row, fp16 in-place
__global__ __launch_bounds__(256) void nonlin16_kernel(f16* __restrict__ qkv,
                                                       const float* __restrict__ inv_s,
                                                       const float* __restrict__ ff) {
  const int t = threadIdx.x, lane = t & 63, w = t >> 6;
  const int row = blockIdx.x * 4 + w;
  f16* qr = qkv + (size_t)row * 1536 + lane * 8;
  f16* kr = qr + 512;
  f16x8 qh = *(const f16x8*)qr;
  f16x8 kh = *(const f16x8*)kr;
  float is[8], fv[8];
  *(float4*)&is[0] = *(const float4*)(inv_s + lane * 8);
  *(float4*)&is[4] = *(const float4*)(inv_s + lane * 8 + 4);
  *(float4*)&fv[0] = *(const float4*)(ff + lane * 8);
  *(float4*)&fv[4] = *(const float4*)(ff + lane * 8 + 4);

  float qv[8], kval[8], sq = 0.f, sk = 0.f;
#pragma unroll
  for (int i = 0; i < 8; ++i) {
    qv[i] = (fmaxf((float)qh[i], 0.f) + 1e-6f) * is[i];
    kval[i] = (fmaxf((float)kh[i], 0.f) + 1e-6f) * is[i];
    sq += qv[i] * qv[i];
    sk += kval[i] * kval[i];
  }
#pragma unroll
  for (int off = 1; off < 64; off <<= 1) {
    sq += __shfl_xor(sq, off);
    sk += __shfl_xor(sk, off);
  }
  const float qn = sqrtf(sq), kn = sqrtf(sk);

  float pq[8], pk[8], sq2 = 0.f, sk2 = 0.f;
#pragma unroll
  for (int i = 0; i < 8; ++i) {
    pq[i] = fast_pow(qv[i], fv[i]);
    pk[i] = fast_pow(kval[i], fv[i]);
    sq2 += pq[i] * pq[i];
    sk2 += pk[i] * pk[i];
  }
#pragma unroll
  for (int off = 1; off < 64; off <<= 1) {
    sq2 += __shfl_xor(sq2, off);
    sk2 += __shfl_xor(sk2, off);
  }
  const float qs = qn / sqrtf(sq2), ks = kn / sqrtf(sk2);
  f16x8 qo, ko;
#pragma unroll
  for (int i = 0; i < 8; ++i) {
    qo[i] = (f16)(pq[i] * qs);
    ko[i] = (f16)(pk[i] * ks);
  }
  *(f16x8*)qr = qo;
  *(f16x8*)kr = ko;
}

// ---------------------------------------------------------------- kv_mat[bh] = k^T v / N  (+ fused ksum), fp16 inputs
__global__ __launch_bounds__(256, 4) void kvmat16_kernel(const f16* __restrict__ qkv,
                                                         float* __restrict__ kvm,
                                                         float* __restrict__ ksum) {
  __shared__ float tile[64 * 66];
  const int bh = blockIdx.y;
  const int b = bh >> 3, h = bh & 7;
  const int chunk = blockIdx.x;
  const int t = threadIdx.x, lane = t & 63, w = t >> 6;
  const int r0 = lane >> 3;
  const int c0 = lane & 7;
  float acc[8][8] = {};
  float kacc = 0.f;
  const size_t base = ((size_t)b * N_TOK + (size_t)chunk * 512 + w * 128) * 1536 + 512 + h * 64;
  const f16* kp = qkv + base + lane;
  const f16* vp = qkv + base + 512 + lane;

  float kcur = (float)kp[0], vcur = (float)vp[0];
  auto body = [&](float kc, float vc) {
    kacc += kc;
    float kk[8], vv[8];
#pragma unroll
    for (int i = 0; i < 8; ++i) {
      kk[i] = __shfl(kc, r0 + i * 8);
      vv[i] = __shfl(vc, c0 + i * 8);
    }
#pragma unroll
    for (int i = 0; i < 8; ++i)
#pragma unroll
      for (int j = 0; j < 8; ++j)
        acc[i][j] = fmaf(kk[i], vv[j], acc[i][j]);
  };
  for (int r = 0; r < 127; ++r) {
    const float knx = (float)kp[(size_t)(r + 1) * 1536];
    const float vnx = (float)vp[(size_t)(r + 1) * 1536];
    body(kcur, vcur);
    kcur = knx; vcur = vnx;
  }
  body(kcur, vcur);

  atomicAdd(&ksum[b * 512 + h * 64 + lane], kacc);

  for (int ww = 0; ww < 4; ++ww) {
    if (w == ww) {
#pragma unroll
      for (int i = 0; i < 8; ++i)
#pragma unroll
        for (int j = 0; j < 8; ++j) {
          const int a = (r0 + i * 8) * 66 + c0 + j * 8;
          tile[a] = (ww == 0) ? acc[i][j] : tile[a] + acc[i][j];
        }
    }
    __syncthreads();
  }
  const float scl = 1.0f / (float)N_TOK;
#pragma unroll
  for (int i = 0; i < 16; ++i) {
    const int idx = i * 256 + t;
    const int rr = idx >> 6, cc = idx & 63;
    atomicAdd(&kvm[(size_t)bh * 4096 + idx], tile[rr * 66 + cc] * scl);
  }
}

// ---------------------------------------------------------------- attn with fused z (fp16 q in, perm fp16 y out)
__global__ __launch_bounds__(256) void attn_fz_kernel(const f16* __restrict__ qkv,
                                                      const float* __restrict__ kvm,
                                                      const float* __restrict__ ksum,
                                                      f16* __restrict__ y16) {
  __shared__ float km[64][64];
  __shared__ float qs[64][64];
  __shared__ float kms[64];
  __shared__ float zl[64];
  const int bh = blockIdx.y;
  const int b = bh >> 3, h = bh & 7;
  const int tok0 = blockIdx.x * 64;
  const int t = threadIdx.x;
  const size_t kvm_base = (size_t)bh * 4096;
#pragma unroll
  for (int i = 0; i < 16; ++i) {
    int idx = i * 256 + t;
    km[idx >> 6][idx & 63] = kvm[kvm_base + idx];
  }
#pragma unroll
  for (int i = 0; i < 4; ++i) {
    const int idx = i * 256 + t;           // 1024 f16x4 chunks = 64x64
    const int tok = idx >> 4, c4 = (idx & 15) * 4;
    f16x4 hv = *(const f16x4*)&qkv[((size_t)(b * N_TOK) + tok0 + tok) * 1536 + h * 64 + c4];
    qs[tok][c4 + 0] = (float)hv.x;
    qs[tok][c4 + 1] = (float)hv.y;
    qs[tok][c4 + 2] = (float)hv.z;
    qs[tok][c4 + 3] = (float)hv.w;
  }
  if (t < 64) kms[t] = ksum[b * 512 + h * 64 + t];
  __syncthreads();

  {
    const int tok = t >> 2, dq = (t & 3) * 16;
    float p = 0.f;
#pragma unroll
    for (int i = 0; i < 16; ++i) p += qs[tok][dq + i] * kms[dq + i];
    p += __shfl_xor(p, 1);
    p += __shfl_xor(p, 2);
    if ((t & 3) == 0) zl[tok] = 1.0f / (p * (1.0f / (float)N_TOK) + 1e-6f);
  }
  __syncthreads();

  const int d = t & 63, slot = t >> 6;
  const int col = h * 64 + d;
  for (int i = 0; i < 16; ++i) {
    const int tok = i * 4 + slot;
    float a0 = 0.f, a1 = 0.f, a2 = 0.f, a3 = 0.f;
#pragma unroll
    for (int din = 0; din < 64; din += 4) {
      a0 = fmaf(qs[tok][din + 0], km[din + 0][d], a0);
      a1 = fmaf(qs[tok][din + 1], km[din + 1][d], a1);
      a2 = fmaf(qs[tok][din + 2], km[din + 2][d], a2);
      a3 = fmaf(qs[tok][din + 3], km[din + 3][d], a3);
    }
    const float val = ((a0 + a1) + (a2 + a3)) * zl[tok];
    const int r = (int)(b * N_TOK) + tok0 + tok;
    y16[(size_t)r * 512 + perm_col(col, r)] = (f16)val;
  }
}

// ---------------------------------------------------------------- depthwise 5x5 conv on v (fp16 in), RMW perm y16
__global__ __launch_bounds__(256, 4) void conv_kernel(const f16* __restrict__ qkv,
                                                      f16* __restrict__ y16,
                                                      const float* __restrict__ wconv,
                                                      const float* __restrict__ bconv) {
  __shared__ float vt[20 * 20 * 16];
  const int zidx = blockIdx.z;
  const int bh = zidx >> 2, cq = zidx & 3;
  const int b = bh >> 3, h = bh & 7;
  const int c0 = cq * 16;
  const int tx0 = blockIdx.x * 16, ty0 = blockIdx.y * 16;
  const int t = threadIdx.x;
  const size_t vcol = 1024 + h * 64 + c0;
#pragma unroll
  for (int i = 0; i < 7; ++i) {
    const int idx = i * 256 + t;
    if (idx < 1600) {
      const int pix = idx >> 2, c4 = (idx & 3) * 4;
      const int lx = pix % 20, ly = pix / 20;
      const int gx = tx0 + lx - 2, gy = ty0 + ly - 2;
      float4 val = make_float4(0.f, 0.f, 0.f, 0.f);
      if ((unsigned)gx < 128u && (unsigned)gy < 128u) {
        f16x4 hv = *(const f16x4*)&qkv[((size_t)(b * N_TOK) + gy * 128 + gx) * 1536 + vcol + c4];
        val = make_float4((float)hv.x, (float)hv.y, (float)hv.z, (float)hv.w);
      }
      *(float4*)&vt[pix * 16 + c4] = val;
    }
  }
  const int c = t & 15;
  const int dd = c0 + c;
  float w[25];
#pragma unroll
  for (int k = 0; k < 25; ++k) w[k] = wconv[dd * 25 + k];
  const float bb = bconv[dd];
  __syncthreads();
  const int slot = t >> 4;
  const int col = h * 64 + dd;
  for (int i = 0; i < 16; ++i) {
    const int pix = i * 16 + slot;
    const int px = pix & 15, py = pix >> 4;
    float acc = bb;
#pragma unroll
    for (int ky = 0; ky < 5; ++ky)
#pragma unroll
      for (int kx = 0; kx < 5; ++kx)
        acc = fmaf(w[ky * 5 + kx], vt[((py + ky) * 20 + (px + kx)) * 16 + c], acc);
    const int r = (int)(b * N_TOK) + (ty0 + py) * 128 + (tx0 + px);
    f16* p = &y16[(size_t)r * 512 + perm_col(col, r)];
    *p = (f16)((float)*p + acc);
  }
}

// ---------------------------------------------------------------- launch
extern "C" void kernel_launch(void* const* d_in, const int* in_sizes, int n_in,
                              void* d_out, int out_size, void* d_ws, size_t ws_size,
                              hipStream_t stream) {
  (void)n_in; (void)out_size;
  const float* x     = (const float*)d_in[0];
  const float* Wq    = (const float*)d_in[1];
  const float* bq    = (const float*)d_in[2];
  const float* Wkv   = (const float*)d_in[3];
  const float* bkv   = (const float*)d_in[4];
  const float* Wp    = (const float*)d_in[5];
  const float* bp    = (const float*)d_in[6];
  const float* ff    = (const float*)d_in[7];
  const float* scale = (const float*)d_in[8];
  const float* dwc_w = (const float*)d_in[9];
  const float* dwc_b = (const float*)d_in[10];

  const int B = in_sizes[0] / (N_TOK * CDIM);   // 4
  const int M = B * N_TOK;                      // 65536

  // ws layout (256.6 MB, well under the known-good 405.3 MB):
  //   qkv16 [M][1536] fp16 (q|k|v) | y16 [M][512] fp16 perm | ksum | kvm | scratch
  f16*   qkv16 = (f16*)d_ws;
  f16*   y16   = qkv16 + (size_t)M * 1536;
  float* ksum  = (float*)(y16 + (size_t)M * 512);
  float* kvm   = ksum + (size_t)B * 512;
  float* zscr  = kvm + (size_t)B * 8 * 4096;

  size_t need = ((size_t)M * 1536 + (size_t)B * 512 + (size_t)B * 8 * 4096 +
                 (size_t)B * 8 * N_TOK) * sizeof(float);   // old known-good bound
  if (ws_size < need) {
    fprintf(stderr, "kernel_launch: ws too small (%zu < %zu)\n", ws_size, need);
    return;
  }

  // d_out head carve (dead until final GEMM): x16 (64 MB) + wqkv16 (1.5 MB)
  f16* x16    = (f16*)d_out;
  f16* wqkv16 = x16 + (size_t)M * 512;
  // z-scratch carve: wp16 (0.5 MB) + inv_s
  f16* wp16   = (f16*)zscr;
  float* inv_s = zscr + 131072;

  const int nsmall = B * 512 + B * 8 * 4096;
  zero_kernel<<<(nsmall + 255) / 256, 256, 0, stream>>>(ksum, nsmall);
  sp_kernel<<<2, 256, 0, stream>>>(scale, inv_s);
  cvt_perm_kernel<<<4096, 256, 0, stream>>>(x, x16, M * 512 / 4);
  cvt_perm_kernel<<<256, 256, 0, stream>>>(Wq, wqkv16, 512 * 512 / 4);
  cvt_perm_kernel<<<512, 256, 0, stream>>>(Wkv, wqkv16 + 512 * 512, 1024 * 512 / 4);
  cvt_perm_kernel<<<256, 256, 0, stream>>>(Wp, wp16, 512 * 512 / 4);

  // fused q+kv projection -> fp16 qkv16 [M][1536]
  gemm_f16<1><<<(M / 128) * 12, 256, 0, stream>>>(x16, wqkv16, bq, bkv,
                                                  nullptr, qkv16, CDIM, 12, 512, 1536);

  nonlin16_kernel<<<M / 4, 256, 0, stream>>>(qkv16, inv_s, ff);
  kvmat16_kernel<<<dim3(32, B * 8), 256, 0, stream>>>(qkv16, kvm, ksum);
  attn_fz_kernel<<<dim3(N_TOK / 64, B * 8), 256, 0, stream>>>(qkv16, kvm, ksum, y16);
  conv_kernel<<<dim3(8, 8, B * 8 * 4), 256, 0, stream>>>(qkv16, y16, dwc_w, dwc_b);

  // output projection: fp32 into d_out (overwrites dead x16/wqkv16)
  gemm_f16<0><<<(M / 128) * 4, 256, 0, stream>>>(y16, wp16, bp, bp,
                                                 (float*)d_out, nullptr, CDIM, 4, 512, 512);
}

// Round 14
// 505.207 us; speedup vs baseline: 4.3791x; 1.1906x over previous
//
#include <hip/hip_runtime.h>
#include <cstdio>

#define N_TOK 16384
#define CDIM  512

typedef unsigned short ushort_t;
typedef _Float16 f16;
typedef __attribute__((ext_vector_type(8))) _Float16 f16x8;
typedef __attribute__((ext_vector_type(4))) _Float16 f16x4;
typedef __attribute__((ext_vector_type(4))) float f32x4;

// ---------------------------------------------------------------- helpers
__device__ __forceinline__ float fast_pow(float x, float p) {
  return __builtin_amdgcn_exp2f(p * __builtin_amdgcn_logf(x));
}
__device__ __forceinline__ void gl_lds16(const void* g, void* l) {
  __builtin_amdgcn_global_load_lds((const __attribute__((address_space(1))) void*)g,
                                   (__attribute__((address_space(3))) void*)l, 16, 0, 0);
}
// permuted fp16 column index (must match cvt_perm_kernel): row r, col k
__device__ __forceinline__ int perm_col(int k, int r) {
  const int kg = k >> 5, c8 = (k >> 3) & 3, e = k & 7;
  return kg * 32 + ((c8 ^ ((r >> 1) & 3)) * 8) + e;
}

// ---------------------------------------------------------------- zero
__global__ void zero_kernel(float* __restrict__ p, int n) {
  int i = blockIdx.x * blockDim.x + threadIdx.x;
  if (i < n) p[i] = 0.f;
}

// ---------------------------------------------------------------- 1/softplus(scale), 512 values
__global__ void sp_kernel(const float* __restrict__ scale, float* __restrict__ inv_s) {
  int i = blockIdx.x * blockDim.x + threadIdx.x;
  if (i < 512) {
    float sc = scale[i];
    float s = (sc > 20.f) ? sc : log1pf(expf(sc));
    inv_s[i] = 1.0f / s;
  }
}

// ---------------------------------------------------------------- fp32 -> fp16, chunk-permuted (512-col rows)
__global__ __launch_bounds__(256) void cvt_perm_kernel(const float* __restrict__ in,
                                                       f16* __restrict__ out, int n4) {
  int i = blockIdx.x * blockDim.x + threadIdx.x;
  const int stride = gridDim.x * blockDim.x;
  for (; i < n4; i += stride) {
    float4 v = ((const float4*)in)[i];
    const int r = i >> 7;
    const int f = i & 127;
    const int kg = f >> 3;
    const int c = (f >> 1) & 3;
    const int e = (f & 1) * 4;
    const int dst = r * 512 + kg * 32 + ((c ^ ((r >> 1) & 3)) * 8) + e;
    f16x4 h;
    h.x = (f16)v.x; h.y = (f16)v.y; h.z = (f16)v.z; h.w = (f16)v.w;
    *(f16x4*)&out[dst] = h;
  }
}

// ---------------------------------------------------------------- fp16 MFMA GEMM, full-DMA
template <int OUT16>
__global__ __launch_bounds__(256, 4) void gemm_f16(const f16* __restrict__ A,
                                                   const f16* __restrict__ Bw,
                                                   const float* __restrict__ b1,
                                                   const float* __restrict__ b2,
                                                   float* __restrict__ C32,
                                                   f16* __restrict__ C16,
                                                   const int K, const int nY,
                                                   const int ncol1, const int ldc) {
  __shared__ __align__(16) f16 SMEM[16896];
  const int t = threadIdx.x;
  const int lane = t & 63;
  const int w = t >> 6;
  const int wr = w >> 1, wc = w & 1;

  const int id = blockIdx.x;
  const int xcd = id & 7;
  const int j = id >> 3;
  const int xpc = (int)(gridDim.x) / (nY * 8);
  const int xloc = j / nY;
  const int y = j - xloc * nY;
  const size_t bm = (size_t)(xcd * xpc + xloc) * 128;
  const int bn = y * 128;

  const int lr = lane & 15;
  const int ksl = lane >> 4;

  f32x4 acc[4][4] = {};

  auto stage = [&](int k0, int buf) {
    const int rsub = lane >> 2;
    const int csub = (lane & 3) * 8;
    const size_t ga = (bm + w * 32 + rsub) * (size_t)K + k0 + csub;
    const size_t gb = ((size_t)(bn + w * 32 + rsub)) * K + k0 + csub;
    f16* Ab = SMEM + buf * 4096;
    f16* Bb = SMEM + 8192 + buf * 4096;
    gl_lds16(A + ga,                   Ab + (w * 32) * 32);
    gl_lds16(A + ga + 16 * (size_t)K,  Ab + (w * 32 + 16) * 32);
    gl_lds16(Bw + gb,                  Bb + (w * 32) * 32);
    gl_lds16(Bw + gb + 16 * (size_t)K, Bb + (w * 32 + 16) * 32);
  };

  const int nsteps = K >> 5;
  stage(0, 0);
  for (int s = 0; s < nsteps; ++s) {
    const int buf = s & 1;
    __syncthreads();
    const f16* Ab = SMEM + buf * 4096;
    const f16* Bb = SMEM + 8192 + buf * 4096;
    f16x8 a[4], b[4];
#pragma unroll
    for (int i = 0; i < 4; ++i) {
      const int rA = wr * 64 + i * 16 + lr;
      a[i] = *(const f16x8*)&Ab[rA * 32 + ((ksl ^ ((rA >> 1) & 3)) * 8)];
      const int rB = wc * 64 + i * 16 + lr;
      b[i] = *(const f16x8*)&Bb[rB * 32 + ((ksl ^ ((rB >> 1) & 3)) * 8)];
    }
    if (s + 1 < nsteps) stage((s + 1) << 5, buf ^ 1);
#pragma unroll
    for (int mi = 0; mi < 4; ++mi)
#pragma unroll
      for (int ni = 0; ni < 4; ++ni)
        acc[mi][ni] = __builtin_amdgcn_mfma_f32_16x16x32_f16(a[mi], b[ni], acc[mi][ni], 0, 0, 0);
  }

  const int rg = (lane >> 4) << 2;
  if (OUT16) {
    __syncthreads();
#pragma unroll
    for (int ni = 0; ni < 4; ++ni) {
      const int cl = wc * 64 + ni * 16 + lr;
      const int cg = bn + cl;
      const float bs = (cg < ncol1) ? b1[cg] : b2[cg - ncol1];
#pragma unroll
      for (int mi = 0; mi < 4; ++mi)
#pragma unroll
        for (int j2 = 0; j2 < 4; ++j2)
          SMEM[(wr * 64 + mi * 16 + rg + j2) * 132 + cl] = (f16)(acc[mi][ni][j2] + bs);
    }
    __syncthreads();
#pragma unroll
    for (int i = 0; i < 8; ++i) {
      const int idx = i * 256 + t;
      const int rl = idx >> 4, ch = (idx & 15) * 8;
      *(f16x8*)&C16[(bm + rl) * (size_t)ldc + bn + ch] = *(const f16x8*)&SMEM[rl * 132 + ch];
    }
  } else {
#pragma unroll
    for (int ni = 0; ni < 4; ++ni) {
      const int col = bn + wc * 64 + ni * 16 + lr;
      const float bs = (col < ncol1) ? b1[col] : b2[col - ncol1];
#pragma unroll
      for (int mi = 0; mi < 4; ++mi) {
        float* Cp = C32 + (bm + wr * 64 + mi * 16 + rg) * (size_t)ldc + col;
#pragma unroll
        for (int j2 = 0; j2 < 4; ++j2)
          Cp[(size_t)j2 * ldc] = acc[mi][ni][j2] + bs;
      }
    }
  }
}

// ---------------------------------------------------------------- nonlinearity, wave-per-row, fp16 in-place
__global__ __launch_bounds__(256) void nonlin16_kernel(f16* __restrict__ qkv,
                                                       const float* __restrict__ inv_s,
                                                       const float* __restrict__ ff) {
  const int t = threadIdx.x, lane = t & 63, w = t >> 6;
  const int row = blockIdx.x * 4 + w;
  f16* qr = qkv + (size_t)row * 1536 + lane * 8;
  f16* kr = qr + 512;
  f16x8 qh = *(const f16x8*)qr;
  f16x8 kh = *(const f16x8*)kr;
  float is[8], fv[8];
  *(float4*)&is[0] = *(const float4*)(inv_s + lane * 8);
  *(float4*)&is[4] = *(const float4*)(inv_s + lane * 8 + 4);
  *(float4*)&fv[0] = *(const float4*)(ff + lane * 8);
  *(float4*)&fv[4] = *(const float4*)(ff + lane * 8 + 4);

  float qv[8], kval[8], sq = 0.f, sk = 0.f;
#pragma unroll
  for (int i = 0; i < 8; ++i) {
    qv[i] = (fmaxf((float)qh[i], 0.f) + 1e-6f) * is[i];
    kval[i] = (fmaxf((float)kh[i], 0.f) + 1e-6f) * is[i];
    sq += qv[i] * qv[i];
    sk += kval[i] * kval[i];
  }
#pragma unroll
  for (int off = 1; off < 64; off <<= 1) {
    sq += __shfl_xor(sq, off);
    sk += __shfl_xor(sk, off);
  }
  const float qn = sqrtf(sq), kn = sqrtf(sk);

  float pq[8], pk[8], sq2 = 0.f, sk2 = 0.f;
#pragma unroll
  for (int i = 0; i < 8; ++i) {
    pq[i] = fast_pow(qv[i], fv[i]);
    pk[i] = fast_pow(kval[i], fv[i]);
    sq2 += pq[i] * pq[i];
    sk2 += pk[i] * pk[i];
  }
#pragma unroll
  for (int off = 1; off < 64; off <<= 1) {
    sq2 += __shfl_xor(sq2, off);
    sk2 += __shfl_xor(sk2, off);
  }
  const float qs = qn / sqrtf(sq2), ks = kn / sqrtf(sk2);
  f16x8 qo, ko;
#pragma unroll
  for (int i = 0; i < 8; ++i) {
    qo[i] = (f16)(pq[i] * qs);
    ko[i] = (f16)(pk[i] * ks);
  }
  *(f16x8*)qr = qo;
  *(f16x8*)kr = ko;
}

// ---------------------------------------------------------------- kv_mat[bh] = k^T v / N  (+ fused ksum), fp16 inputs
__global__ __launch_bounds__(256, 4) void kvmat16_kernel(const f16* __restrict__ qkv,
                                                         float* __restrict__ kvm,
                                                         float* __restrict__ ksum) {
  __shared__ float tile[64 * 66];
  const int bh = blockIdx.y;
  const int b = bh >> 3, h = bh & 7;
  const int chunk = blockIdx.x;
  const int t = threadIdx.x, lane = t & 63, w = t >> 6;
  const int r0 = lane >> 3;
  const int c0 = lane & 7;
  float acc[8][8] = {};
  float kacc = 0.f;
  const size_t base = ((size_t)b * N_TOK + (size_t)chunk * 512 + w * 128) * 1536 + 512 + h * 64;
  const f16* kp = qkv + base + lane;
  const f16* vp = qkv + base + 512 + lane;

  float kcur = (float)kp[0], vcur = (float)vp[0];
  auto body = [&](float kc, float vc) {
    kacc += kc;
    float kk[8], vv[8];
#pragma unroll
    for (int i = 0; i < 8; ++i) {
      kk[i] = __shfl(kc, r0 + i * 8);
      vv[i] = __shfl(vc, c0 + i * 8);
    }
#pragma unroll
    for (int i = 0; i < 8; ++i)
#pragma unroll
      for (int j = 0; j < 8; ++j)
        acc[i][j] = fmaf(kk[i], vv[j], acc[i][j]);
  };
  for (int r = 0; r < 127; ++r) {
    const float knx = (float)kp[(size_t)(r + 1) * 1536];
    const float vnx = (float)vp[(size_t)(r + 1) * 1536];
    body(kcur, vcur);
    kcur = knx; vcur = vnx;
  }
  body(kcur, vcur);

  atomicAdd(&ksum[b * 512 + h * 64 + lane], kacc);

  for (int ww = 0; ww < 4; ++ww) {
    if (w == ww) {
#pragma unroll
      for (int i = 0; i < 8; ++i)
#pragma unroll
        for (int j = 0; j < 8; ++j) {
          const int a = (r0 + i * 8) * 66 + c0 + j * 8;
          tile[a] = (ww == 0) ? acc[i][j] : tile[a] + acc[i][j];
        }
    }
    __syncthreads();
  }
  const float scl = 1.0f / (float)N_TOK;
#pragma unroll
  for (int i = 0; i < 16; ++i) {
    const int idx = i * 256 + t;
    const int rr = idx >> 6, cc = idx & 63;
    atomicAdd(&kvm[(size_t)bh * 4096 + idx], tile[rr * 66 + cc] * scl);
  }
}

// ---------------------------------------------------------------- kvm fp32 -> transposed, chunk-swizzled fp16
// kvmT16[bh][d][ (c ^ (d&7))*8 + e ] = kvm[bh][din= c*8+e][d]
__global__ void cvt_kvmT_kernel(const float* __restrict__ kvm, f16* __restrict__ kvmT16) {
  const int bh = blockIdx.x, t = threadIdx.x;
#pragma unroll
  for (int i = 0; i < 16; ++i) {
    const int e = i * 256 + t;            // 0..4095 = din*64 + d
    const int din = e >> 6, d = e & 63;
    const float v = kvm[(size_t)bh * 4096 + e];
    const int c = din >> 3, ce = din & 7;
    kvmT16[(size_t)bh * 4096 + d * 64 + ((c ^ (d & 7)) * 8) + ce] = (f16)v;
  }
}

// ---------------------------------------------------------------- MFMA attention: y = (q @ kvm) * z, perm fp16 out
// Reg-staged (no async DMA): f16x8 global loads, swizzle applied on LDS store,
// matching XOR on read (both-sides swizzle). 4 waves x (2 tok x 4 d frags) x K=64.
__global__ __launch_bounds__(256, 4) void attn_mfma_kernel(const f16* __restrict__ qkv,
                                                           const f16* __restrict__ kvmT16,
                                                           const float* __restrict__ ksum,
                                                           f16* __restrict__ y16) {
  __shared__ __align__(16) f16 QS[128 * 64];   // [row][chunk ^ (row&7)]
  __shared__ __align__(16) f16 KM[64 * 64];    // [d][chunk ^ (d&7)] (pre-swizzled in global)
  __shared__ float kms[64];
  __shared__ float zl[128];
  const int bh = blockIdx.y;
  const int b = bh >> 3, h = bh & 7;
  const int tok0 = blockIdx.x * 128;
  const int t = threadIdx.x, lane = t & 63, w = t >> 6;

  // Q: 1024 chunks (128 rows x 8 chunks of 8 f16); coalesced loads, swizzled stores
#pragma unroll
  for (int i = 0; i < 4; ++i) {
    const int idx = i * 256 + t;
    const int row = idx >> 3, ch = idx & 7;
    const f16x8 v = *(const f16x8*)&qkv[((size_t)(b * N_TOK) + tok0 + row) * 1536 + h * 64 + ch * 8];
    *(f16x8*)&QS[row * 64 + ((ch ^ (row & 7)) * 8)] = v;
  }
  // KM: verbatim vectorized copy (kvmT16 already transposed + swizzled)
#pragma unroll
  for (int i = 0; i < 2; ++i) {
    const int idx = i * 256 + t;
    *(f16x8*)&KM[idx * 8] = *(const f16x8*)&kvmT16[(size_t)bh * 4096 + idx * 8];
  }
  if (t < 64) kms[t] = ksum[b * 512 + h * 64 + t];
  __syncthreads();

  // z per token: 2 threads/token, 32 din each
  {
    const int tok = t >> 1;
    const int ch0 = (t & 1) * 4;
    float p = 0.f;
#pragma unroll
    for (int c = 0; c < 4; ++c) {
      const int ch = ch0 + c;
      const f16x8 hv = *(const f16x8*)&QS[tok * 64 + ((ch ^ (tok & 7)) * 8)];
#pragma unroll
      for (int e = 0; e < 8; ++e) p += (float)hv[e] * kms[ch * 8 + e];
    }
    p += __shfl_xor(p, 1);
    if ((t & 1) == 0) zl[tok] = 1.0f / (p * (1.0f / (float)N_TOK) + 1e-6f);
  }
  __syncthreads();

  // fragments + MFMA
  const int lr = lane & 15, ksl = lane >> 4;
  f32x4 acc[2][4] = {};
#pragma unroll
  for (int s = 0; s < 2; ++s) {
    f16x8 a[2], bfr[4];
#pragma unroll
    for (int mi = 0; mi < 2; ++mi) {
      const int row = w * 32 + mi * 16 + lr;
      a[mi] = *(const f16x8*)&QS[row * 64 + (((s * 4 + ksl) ^ (row & 7)) * 8)];
    }
#pragma unroll
    for (int ni = 0; ni < 4; ++ni) {
      const int dr = ni * 16 + lr;
      bfr[ni] = *(const f16x8*)&KM[dr * 64 + (((s * 4 + ksl) ^ (dr & 7)) * 8)];
    }
#pragma unroll
    for (int mi = 0; mi < 2; ++mi)
#pragma unroll
      for (int ni = 0; ni < 4; ++ni)
        acc[mi][ni] = __builtin_amdgcn_mfma_f32_16x16x32_f16(a[mi], bfr[ni], acc[mi][ni], 0, 0, 0);
  }

  // epilogue: row = tokens, col = d (C/D layout col=lane&15, row=(lane>>4)*4+reg)
  const int rg = (lane >> 4) << 2;
#pragma unroll
  for (int mi = 0; mi < 2; ++mi)
#pragma unroll
    for (int ni = 0; ni < 4; ++ni)
#pragma unroll
      for (int j2 = 0; j2 < 4; ++j2) {
        const int row = w * 32 + mi * 16 + rg + j2;
        const int dcol = ni * 16 + lr;
        const float val = acc[mi][ni][j2] * zl[row];
        const int r = (int)(b * N_TOK) + tok0 + row;
        y16[(size_t)r * 512 + perm_col(h * 64 + dcol, r)] = (f16)val;
      }
}

// ---------------------------------------------------------------- depthwise 5x5 conv on v (fp16 in), RMW perm y16
__global__ __launch_bounds__(256, 4) void conv_kernel(const f16* __restrict__ qkv,
                                                      f16* __restrict__ y16,
                                                      const float* __restrict__ wconv,
                                                      const float* __restrict__ bconv) {
  __shared__ float vt[20 * 20 * 16];
  const int zidx = blockIdx.z;
  const int bh = zidx >> 2, cq = zidx & 3;
  const int b = bh >> 3, h = bh & 7;
  const int c0 = cq * 16;
  const int tx0 = blockIdx.x * 16, ty0 = blockIdx.y * 16;
  const int t = threadIdx.x;
  const size_t vcol = 1024 + h * 64 + c0;
#pragma unroll
  for (int i = 0; i < 7; ++i) {
    const int idx = i * 256 + t;
    if (idx < 1600) {
      const int pix = idx >> 2, c4 = (idx & 3) * 4;
      const int lx = pix % 20, ly = pix / 20;
      const int gx = tx0 + lx - 2, gy = ty0 + ly - 2;
      float4 val = make_float4(0.f, 0.f, 0.f, 0.f);
      if ((unsigned)gx < 128u && (unsigned)gy < 128u) {
        f16x4 hv = *(const f16x4*)&qkv[((size_t)(b * N_TOK) + gy * 128 + gx) * 1536 + vcol + c4];
        val = make_float4((float)hv.x, (float)hv.y, (float)hv.z, (float)hv.w);
      }
      *(float4*)&vt[pix * 16 + c4] = val;
    }
  }
  const int c = t & 15;
  const int dd = c0 + c;
  float w[25];
#pragma unroll
  for (int k = 0; k < 25; ++k) w[k] = wconv[dd * 25 + k];
  const float bb = bconv[dd];
  __syncthreads();
  const int slot = t >> 4;
  const int col = h * 64 + dd;
  for (int i = 0; i < 16; ++i) {
    const int pix = i * 16 + slot;
    const int px = pix & 15, py = pix >> 4;
    float acc = bb;
#pragma unroll
    for (int ky = 0; ky < 5; ++ky)
#pragma unroll
      for (int kx = 0; kx < 5; ++kx)
        acc = fmaf(w[ky * 5 + kx], vt[((py + ky) * 20 + (px + kx)) * 16 + c], acc);
    const int r = (int)(b * N_TOK) + (ty0 + py) * 128 + (tx0 + px);
    f16* p = &y16[(size_t)r * 512 + perm_col(col, r)];
    *p = (f16)((float)*p + acc);
  }
}

// ---------------------------------------------------------------- launch
extern "C" void kernel_launch(void* const* d_in, const int* in_sizes, int n_in,
                              void* d_out, int out_size, void* d_ws, size_t ws_size,
                              hipStream_t stream) {
  (void)n_in; (void)out_size;
  const float* x     = (const float*)d_in[0];
  const float* Wq    = (const float*)d_in[1];
  const float* bq    = (const float*)d_in[2];
  const float* Wkv   = (const float*)d_in[3];
  const float* bkv   = (const float*)d_in[4];
  const float* Wp    = (const float*)d_in[5];
  const float* bp    = (const float*)d_in[6];
  const float* ff    = (const float*)d_in[7];
  const float* scale = (const float*)d_in[8];
  const float* dwc_w = (const float*)d_in[9];
  const float* dwc_b = (const float*)d_in[10];

  const int B = in_sizes[0] / (N_TOK * CDIM);   // 4
  const int M = B * N_TOK;                      // 65536

  // ws layout: qkv16 [M][1536] fp16 | y16 [M][512] fp16 perm | ksum | kvm | scratch
  f16*   qkv16 = (f16*)d_ws;
  f16*   y16   = qkv16 + (size_t)M * 1536;
  float* ksum  = (float*)(y16 + (size_t)M * 512);
  float* kvm   = ksum + (size_t)B * 512;
  float* zscr  = kvm + (size_t)B * 8 * 4096;

  size_t need = ((size_t)M * 1536 + (size_t)B * 512 + (size_t)B * 8 * 4096 +
                 (size_t)B * 8 * N_TOK) * sizeof(float);   // known-good bound
  if (ws_size < need) {
    fprintf(stderr, "kernel_launch: ws too small (%zu < %zu)\n", ws_size, need);
    return;
  }

  // d_out head carve (dead until final GEMM): x16 (64 MB) + wqkv16 (1.5 MB)
  f16* x16    = (f16*)d_out;
  f16* wqkv16 = x16 + (size_t)M * 512;
  // z-scratch carve: wp16 (512 KB) + inv_s (2 KB) + kvmT16 (256 KB)
  f16* wp16    = (f16*)zscr;
  float* inv_s = zscr + 131072;
  f16* kvmT16  = (f16*)(inv_s + 512);

  const int nsmall = B * 512 + B * 8 * 4096;
  zero_kernel<<<(nsmall + 255) / 256, 256, 0, stream>>>(ksum, nsmall);
  sp_kernel<<<2, 256, 0, stream>>>(scale, inv_s);
  cvt_perm_kernel<<<4096, 256, 0, stream>>>(x, x16, M * 512 / 4);
  cvt_perm_kernel<<<256, 256, 0, stream>>>(Wq, wqkv16, 512 * 512 / 4);
  cvt_perm_kernel<<<512, 256, 0, stream>>>(Wkv, wqkv16 + 512 * 512, 1024 * 512 / 4);
  cvt_perm_kernel<<<256, 256, 0, stream>>>(Wp, wp16, 512 * 512 / 4);

  // fused q+kv projection -> fp16 qkv16 [M][1536]
  gemm_f16<1><<<(M / 128) * 12, 256, 0, stream>>>(x16, wqkv16, bq, bkv,
                                                  nullptr, qkv16, CDIM, 12, 512, 1536);

  nonlin16_kernel<<<M / 4, 256, 0, stream>>>(qkv16, inv_s, ff);
  kvmat16_kernel<<<dim3(32, B * 8), 256, 0, stream>>>(qkv16, kvm, ksum);
  cvt_kvmT_kernel<<<B * 8, 256, 0, stream>>>(kvm, kvmT16);
  attn_mfma_kernel<<<dim3(N_TOK / 128, B * 8), 256, 0, stream>>>(qkv16, kvmT16, ksum, y16);
  conv_kernel<<<dim3(8, 8, B * 8 * 4), 256, 0, stream>>>(qkv16, y16, dwc_w, dwc_b);

  // output projection: fp32 into d_out (overwrites dead x16/wqkv16)
  gemm_f16<0><<<(M / 128) * 4, 256, 0, stream>>>(y16, wp16, bp, bp,
                                                 (float*)d_out, nullptr, CDIM, 4, 512, 512);
}